// Round 1
// baseline (225.001 us; speedup 1.0000x reference)
//
#include <hip/hip_runtime.h>
#include <hip/hip_fp16.h>

#define THREADS 256
#define CHUNK 4096        // edges per binA block
#define NBUCK 391         // buckets of 128 nodes (dst>>7)
#define BCAP  8192        // per-bucket edge capacity (mean 4096, 64 sigma slack)
#define CCAP  (BCAP+2048) // csr region capacity (edges + self + per-row pad to x16)

// gemm1: h = x @ W1 unscaled -> fp16 output. 256 rows/block; thread = 4 rows x 8 cols.
// W1 in LDS (broadcast b128 reads); x staged TRANSPOSED so each lane reads its
// 4 rows with one conflict-free ds_read_b128. No VMEM in the K loop.
__global__ __launch_bounds__(256)
void k_gemm1(const float* __restrict__ x, const float* __restrict__ W,
             __half* __restrict__ h, int N) {
    __shared__ float Wsh[128 * 32];   // 16 KB
    __shared__ float xt[32][257];     // 32.9 KB: [k in chunk][row], pitch 257
    int tid = threadIdx.x;
    int row0 = (int)blockIdx.x * 256;
    int lane = tid & 63;              // rows 4*lane .. 4*lane+3
    int cg = tid >> 6;                // cols cg*8 .. cg*8+7
    for (int j = tid; j < 1024; j += 256)
        reinterpret_cast<float4*>(Wsh)[j] = reinterpret_cast<const float4*>(W)[j];
    const float4 z4 = make_float4(0.f, 0.f, 0.f, 0.f);
    float4 acc0[4], acc1[4];
    #pragma unroll
    for (int j = 0; j < 4; ++j) { acc0[j] = z4; acc1[j] = z4; }
    for (int kc = 0; kc < 128; kc += 32) {
        __syncthreads();
        #pragma unroll
        for (int i = 0; i < 8; ++i) {
            int f = i * 256 + tid;
            int r = f >> 3, c4 = f & 7;   // row 0..255, float4-col 0..7
            int gr = row0 + r;
            float4 vv = (gr < N)
                ? *reinterpret_cast<const float4*>(x + (size_t)gr * 128 + kc + c4 * 4)
                : z4;
            xt[c4*4+0][r] = vv.x; xt[c4*4+1][r] = vv.y;
            xt[c4*4+2][r] = vv.z; xt[c4*4+3][r] = vv.w;
        }
        __syncthreads();
        #pragma unroll
        for (int k = 0; k < 32; ++k) {
            float4 xv = *reinterpret_cast<const float4*>(&xt[k][lane * 4]);
            const float4* wr = reinterpret_cast<const float4*>(Wsh + (kc + k) * 32 + cg * 8);
            float4 w0 = wr[0];   // wave-uniform LDS address -> broadcast
            float4 w1 = wr[1];
            const float* xp = reinterpret_cast<const float*>(&xv);
            #pragma unroll
            for (int j = 0; j < 4; ++j) {
                float xj = xp[j];
                acc0[j].x += xj * w0.x; acc0[j].y += xj * w0.y;
                acc0[j].z += xj * w0.z; acc0[j].w += xj * w0.w;
                acc1[j].x += xj * w1.x; acc1[j].y += xj * w1.y;
                acc1[j].z += xj * w1.z; acc1[j].w += xj * w1.w;
            }
        }
    }
    int rbase = row0 + lane * 4;
    #pragma unroll
    for (int j = 0; j < 4; ++j) {
        int row = rbase + j;
        if (row <= N) {   // row N (pad) gets zeros naturally from zero-staged xt
            __half2 p0 = __floats2half2_rn(acc0[j].x, acc0[j].y);
            __half2 p1 = __floats2half2_rn(acc0[j].z, acc0[j].w);
            __half2 p2 = __floats2half2_rn(acc1[j].x, acc1[j].y);
            __half2 p3 = __floats2half2_rn(acc1[j].z, acc1[j].w);
            uint4 st;
            st.x = *reinterpret_cast<unsigned int*>(&p0);
            st.y = *reinterpret_cast<unsigned int*>(&p1);
            st.z = *reinterpret_cast<unsigned int*>(&p2);
            st.w = *reinterpret_cast<unsigned int*>(&p3);
            *reinterpret_cast<uint4*>(h + (size_t)row * 32 + cg * 8) = st;
        }
    }
}

// binA: 512 threads, 4096 edges/block. Rank -> scan -> LDS stage (bucket-sorted)
// -> contiguous run writes into bucket-owned regions.
__global__ __launch_bounds__(512)
void k_binA(const int* __restrict__ src, const int* __restrict__ dst, int E,
            int* __restrict__ cursor, unsigned int* __restrict__ binned) {
    __shared__ int cnt[512];
    __shared__ int sc[512];
    __shared__ int lbase[512];
    __shared__ int gbs[512];
    __shared__ unsigned int stage[CHUNK];
    int tid = threadIdx.x;
    cnt[tid] = 0;
    __syncthreads();
    int base = (int)blockIdx.x * CHUNK;
    unsigned int pk[8];
    int rk[8];
    unsigned int mask = 0;
    #pragma unroll
    for (int i = 0; i < 2; ++i) {
        int e = base + i * 2048 + tid * 4;
        if (e + 3 < E) {
            int4 d4 = *reinterpret_cast<const int4*>(dst + e);
            int4 s4 = *reinterpret_cast<const int4*>(src + e);
            pk[i*4+0] = ((unsigned)d4.x << 16) | (unsigned)s4.x; rk[i*4+0] = atomicAdd(&cnt[d4.x >> 7], 1);
            pk[i*4+1] = ((unsigned)d4.y << 16) | (unsigned)s4.y; rk[i*4+1] = atomicAdd(&cnt[d4.y >> 7], 1);
            pk[i*4+2] = ((unsigned)d4.z << 16) | (unsigned)s4.z; rk[i*4+2] = atomicAdd(&cnt[d4.z >> 7], 1);
            pk[i*4+3] = ((unsigned)d4.w << 16) | (unsigned)s4.w; rk[i*4+3] = atomicAdd(&cnt[d4.w >> 7], 1);
            mask |= 0xFu << (i * 4);
        } else {
            for (int j = 0; j < 4; ++j) {
                int k = e + j;
                if (k < E) {
                    int d = dst[k], s = src[k];
                    pk[i*4+j] = ((unsigned)d << 16) | (unsigned)s;
                    rk[i*4+j] = atomicAdd(&cnt[d >> 7], 1);
                    mask |= 1u << (i * 4 + j);
                }
            }
        }
    }
    __syncthreads();
    int myc = cnt[tid];
    sc[tid] = myc;
    __syncthreads();
    for (int off = 1; off < 512; off <<= 1) {
        int v = (tid >= off) ? sc[tid - off] : 0;
        __syncthreads();
        sc[tid] += v;
        __syncthreads();
    }
    lbase[tid] = sc[tid] - myc;
    gbs[tid] = myc ? atomicAdd(&cursor[tid], myc) : 0;
    int nvalid = sc[511];
    __syncthreads();
    #pragma unroll
    for (int i = 0; i < 8; ++i) {
        if (mask & (1u << i)) {
            int b = pk[i] >> 23;
            stage[lbase[b] + rk[i]] = pk[i];
        }
    }
    __syncthreads();
    for (int i = tid; i < nvalid; i += 512) {
        unsigned int v = stage[i];
        int b = v >> 23;
        binned[(size_t)b * BCAP + gbs[b] + (i - lbase[b])] = v;
    }
}

// binB: one block per 128-node bucket. Single pass with rank recording.
// Rescale phase now reads/writes the fp16 h buffer (4x less traffic than fp32).
__global__ __launch_bounds__(512)
void k_binB(const unsigned int* __restrict__ binned, const int* __restrict__ cursor,
            int* __restrict__ rowbeg, int* __restrict__ rowend, float* __restrict__ dinvg,
            unsigned short* __restrict__ csr, __half* __restrict__ hh, int N) {
    __shared__ int cnt[128];
    __shared__ int sc[128];
    __shared__ int excls[128];
    __shared__ float dv[128];
    int tid = threadIdx.x;
    int b = blockIdx.x;
    size_t ebase = (size_t)b * BCAP;
    int ne = cursor[b];
    if (tid < 128) cnt[tid] = 0;
    __syncthreads();
    unsigned int pk[16];
    int rk[16];
    #pragma unroll
    for (int ii = 0; ii < 16; ++ii) {
        int i = ii * 512 + tid;
        if (i < ne) {
            pk[ii] = binned[ebase + i];
            rk[ii] = atomicAdd(&cnt[(pk[ii] >> 16) & 127], 1);
        }
    }
    __syncthreads();
    int myc = 0, pcnt = 0;
    if (tid < 128) {
        myc = cnt[tid];
        pcnt = (myc + 1 + 15) & ~15;   // self + edges, padded to x16
        sc[tid] = pcnt;
    }
    __syncthreads();
    for (int off = 1; off < 128; off <<= 1) {
        int v = 0;
        if (tid < 128 && tid >= off) v = sc[tid - off];
        __syncthreads();
        if (tid < 128) sc[tid] += v;
        __syncthreads();
    }
    int cbase = b * CCAP;
    if (tid < 128) {
        int pexcl = sc[tid] - pcnt;
        excls[tid] = pexcl;
        int node = (b << 7) + tid;
        int rb = cbase + pexcl;
        float di = rsqrtf((float)(myc + 1));
        dv[tid] = di;
        if (node < N) {
            rowbeg[node] = rb;
            rowend[node] = rb + pcnt;
            dinvg[node] = di;
            csr[rb] = (unsigned short)node;   // self entry first
        }
    }
    __syncthreads();
    #pragma unroll
    for (int ii = 0; ii < 16; ++ii) {
        int i = ii * 512 + tid;
        if (i < ne) {
            int nl = (pk[ii] >> 16) & 127;
            csr[cbase + excls[nl] + 1 + rk[ii]] = (unsigned short)(pk[ii] & 0xFFFFu);
        }
    }
    __syncthreads();
    if (tid < 128) {   // fill pad slots with dummy node N (zero row)
        int pexcl = excls[tid];
        for (int p = pexcl + 1 + myc; p < pexcl + pcnt; ++p)
            csr[cbase + p] = (unsigned short)N;
    }
    __syncthreads();
    // scale h rows of this bucket by dinv (fp16 in place): 128 rows x 4 uint4
    uint4* h4 = reinterpret_cast<uint4*>(hh);
    size_t hbase = (size_t)(b << 7) * 4;
    {
        int nl = tid >> 2;
        if (((b << 7) + nl) < N) {
            uint4 v = h4[hbase + tid];
            float d = dv[nl];
            __half2* hv = reinterpret_cast<__half2*>(&v);
            #pragma unroll
            for (int t = 0; t < 4; ++t) {
                float2 f = __half22float2(hv[t]);
                hv[t] = __floats2half2_rn(f.x * d, f.y * d);
            }
            h4[hbase + tid] = v;
        }
    }
}

// agg layer1 + bias + relu + gemm2 + dinv pre-scale, fp16 gather payload.
// Row = 64B = 4 uint4 -> 16 source rows per 64-lane gather instruction.
__global__ __launch_bounds__(THREADS)
void k_aggmm1(const __half* __restrict__ hp, const int* __restrict__ rowbeg,
              const int* __restrict__ rowend, const unsigned short* __restrict__ csr,
              const float* __restrict__ dinv, const float* __restrict__ b1,
              const float* __restrict__ W2, __half* __restrict__ hp2, int N) {
    int tid = threadIdx.x;
    int lane = tid & 63;
    int node = blockIdx.x * 4 + (tid >> 6);
    if (node > N) return;
    if (node == N) {   // dummy pad row of hp2: zeros
        if (lane < 4) reinterpret_cast<uint4*>(hp2 + (size_t)N * 32)[lane] =
            make_uint4(0u, 0u, 0u, 0u);
        return;
    }
    int j = lane >> 2, q = lane & 3;   // j: source slot in group of 16, q: 16B chunk
    int beg = rowbeg[node];
    int end = rowend[node];
    float acc[8];
    #pragma unroll
    for (int t = 0; t < 8; ++t) acc[t] = 0.f;
    const uint4* hp4 = reinterpret_cast<const uint4*>(hp);
    for (int base = beg; base < end; base += 64) {
        int idx = base + lane;
        int cv = (idx < end) ? (int)csr[idx] : 0;
        int nin = end - base; if (nin > 64) nin = 64;   // multiple of 16
        for (int c = 0; c < nin; c += 16) {
            int s = __shfl(cv, c + j, 64);
            uint4 v = hp4[(size_t)s * 4 + q];
            const __half2* hv = reinterpret_cast<const __half2*>(&v);
            #pragma unroll
            for (int t = 0; t < 4; ++t) {
                float2 f = __half22float2(hv[t]);
                acc[2*t]   += f.x;
                acc[2*t+1] += f.y;
            }
        }
    }
    // reduce across the 16 j-groups (lanes stride 4 share a q)
    #pragma unroll
    for (int d = 4; d < 64; d <<= 1) {
        #pragma unroll
        for (int t = 0; t < 8; ++t) acc[t] += __shfl_xor(acc[t], d, 64);
    }
    // feature k lives on lanes with q = k>>3, register k&7
    int cp = lane & 31;
    float wcol[32];
    #pragma unroll
    for (int k = 0; k < 32; ++k) wcol[k] = W2[k * 32 + cp];
    float dd = dinv[node];
    float o = 0.f;
    #pragma unroll
    for (int k = 0; k < 32; ++k) {
        float t = __shfl(acc[k & 7], k >> 3, 64);
        float y = fmaxf(t * dd + b1[k], 0.f);
        o += y * wcol[k];
    }
    o *= dd;   // pre-scale for layer-2 aggregation
    float onb = __shfl_xor(o, 1, 64);
    if (lane < 32 && (cp & 1) == 0) {
        __half2 p = __floats2half2_rn(o, onb);
        *reinterpret_cast<__half2*>(hp2 + (size_t)node * 32 + cp) = p;
    }
}

// agg layer2 + bias + relu + head, fp16 gather payload.
__global__ __launch_bounds__(THREADS)
void k_aggout(const __half* __restrict__ hp, const int* __restrict__ rowbeg,
              const int* __restrict__ rowend, const unsigned short* __restrict__ csr,
              const float* __restrict__ dinv, const float* __restrict__ b2,
              const float* __restrict__ Wo, const float* __restrict__ bo,
              float* __restrict__ out, int N) {
    int tid = threadIdx.x;
    int lane = tid & 63;
    int node = blockIdx.x * 4 + (tid >> 6);
    if (node >= N) return;
    int j = lane >> 2, q = lane & 3;
    int beg = rowbeg[node];
    int end = rowend[node];
    float acc[8];
    #pragma unroll
    for (int t = 0; t < 8; ++t) acc[t] = 0.f;
    const uint4* hp4 = reinterpret_cast<const uint4*>(hp);
    for (int base = beg; base < end; base += 64) {
        int idx = base + lane;
        int cv = (idx < end) ? (int)csr[idx] : 0;
        int nin = end - base; if (nin > 64) nin = 64;
        for (int c = 0; c < nin; c += 16) {
            int s = __shfl(cv, c + j, 64);
            uint4 v = hp4[(size_t)s * 4 + q];
            const __half2* hv = reinterpret_cast<const __half2*>(&v);
            #pragma unroll
            for (int t = 0; t < 4; ++t) {
                float2 f = __half22float2(hv[t]);
                acc[2*t]   += f.x;
                acc[2*t+1] += f.y;
            }
        }
    }
    #pragma unroll
    for (int d = 4; d < 64; d <<= 1) {
        #pragma unroll
        for (int t = 0; t < 8; ++t) acc[t] += __shfl_xor(acc[t], d, 64);
    }
    float wcol[32];
    #pragma unroll
    for (int k = 0; k < 32; ++k) wcol[k] = Wo[k * 64 + lane];
    float dd = dinv[node];
    float o = bo[lane];
    #pragma unroll
    for (int k = 0; k < 32; ++k) {
        float t = __shfl(acc[k & 7], k >> 3, 64);
        float y = fmaxf(t * dd + b2[k], 0.f);
        o += y * wcol[k];
    }
    out[(size_t)node * 64 + lane] = o;
}

extern "C" void kernel_launch(void* const* d_in, const int* in_sizes, int n_in,
                              void* d_out, int out_size, void* d_ws, size_t ws_size,
                              hipStream_t stream) {
    const float* x  = (const float*)d_in[0];
    const int*   ei = (const int*)d_in[1];
    const float* W1 = (const float*)d_in[2];
    const float* b1 = (const float*)d_in[3];
    const float* W2 = (const float*)d_in[4];
    const float* b2 = (const float*)d_in[5];
    const float* Wo = (const float*)d_in[6];
    const float* bo = (const float*)d_in[7];
    float* out = (float*)d_out;

    const int N = in_sizes[0] / 128;   // 50000
    const int E = in_sizes[1] / 2;     // 1600000
    const int* src = ei;
    const int* dst = ei + E;

    char* ws = (char*)d_ws;
    size_t off = 0;
    auto alloc = [&](size_t bytes) {
        void* p = ws + off;
        off += (bytes + 255) & ~(size_t)255;
        return p;
    };
    int*            cursor = (int*)           alloc(512 * 4);
    unsigned int*   binned = (unsigned int*)  alloc((size_t)NBUCK * BCAP * 4);
    int*            rowbeg = (int*)           alloc((size_t)N * 4);
    int*            rowend = (int*)           alloc((size_t)N * 4);
    float*          dinv   = (float*)         alloc((size_t)N * 4);
    unsigned short* csr    = (unsigned short*)alloc((size_t)NBUCK * CCAP * 2);
    __half*         bufAh  = (__half*)        alloc((size_t)(N + 1) * 32 * 2);
    __half*         bufBh  = (__half*)        alloc((size_t)(N + 1) * 32 * 2);

    const int nbinA  = (E + CHUNK - 1) / CHUNK;      // 391
    const int nGemm1 = (N + 1 + 255) / 256;          // 196 (covers pad row N)
    const int gAgg1  = (N + 1 + 3) / 4;              // covers node N (zero row)
    const int gAgg2  = (N + 3) / 4;

    hipMemsetAsync(cursor, 0, 512 * 4, stream);
    k_gemm1<<<nGemm1, 256, 0, stream>>>(x, W1, bufAh, N);
    k_binA<<<nbinA, 512, 0, stream>>>(src, dst, E, cursor, binned);
    k_binB<<<NBUCK, 512, 0, stream>>>(binned, cursor, rowbeg, rowend, dinv,
                                      csr, bufAh, N);
    k_aggmm1<<<gAgg1, THREADS, 0, stream>>>(bufAh, rowbeg, rowend, csr, dinv, b1,
                                            W2, bufBh, N);
    k_aggout<<<gAgg2, THREADS, 0, stream>>>(bufBh, rowbeg, rowend, csr, dinv, b2,
                                            Wo, bo, out, N);
}

// Round 2
// 213.793 us; speedup vs baseline: 1.0524x; 1.0524x over previous
//
#include <hip/hip_runtime.h>
#include <hip/hip_fp16.h>

#define THREADS 256
#define CHUNK 4096        // edges per binA block
#define NBUCK 391         // buckets of 128 nodes (dst>>7)
#define BCAP  8192        // per-bucket edge capacity (mean 4096, 64 sigma slack)
#define CCAP  (BCAP+2048) // csr region capacity (edges + self + per-row pad to x16)

// gemm1: h = x @ W1 unscaled -> fp16. 128 rows/block (391 blocks, ~1.5/CU vs 196
// before: grid starvation fix); thread = 2 rows x 8 cols. W1 in LDS (broadcast
// b128); x staged transposed, pitch 130 so float2 row-reads are 8B-aligned.
__global__ __launch_bounds__(256)
void k_gemm1(const float* __restrict__ x, const float* __restrict__ W,
             __half* __restrict__ h, int N) {
    __shared__ float Wsh[128 * 32];   // 16 KB
    __shared__ float xt[32][130];     // 16.3 KB
    int tid = threadIdx.x;
    int row0 = (int)blockIdx.x * 128;
    int lane = tid & 63;              // rows 2*lane, 2*lane+1
    int cg = tid >> 6;                // cols cg*8 .. cg*8+7
    for (int j = tid; j < 1024; j += 256)
        reinterpret_cast<float4*>(Wsh)[j] = reinterpret_cast<const float4*>(W)[j];
    const float4 z4 = make_float4(0.f, 0.f, 0.f, 0.f);
    float4 a00 = z4, a01 = z4, a10 = z4, a11 = z4;
    for (int kc = 0; kc < 128; kc += 32) {
        __syncthreads();
        #pragma unroll
        for (int i = 0; i < 4; ++i) {
            int f = i * 256 + tid;
            int r = f >> 3, c4 = f & 7;   // row 0..127, float4-col 0..7
            int gr = row0 + r;
            float4 vv = (gr < N)
                ? *reinterpret_cast<const float4*>(x + (size_t)gr * 128 + kc + c4 * 4)
                : z4;
            xt[c4*4+0][r] = vv.x; xt[c4*4+1][r] = vv.y;
            xt[c4*4+2][r] = vv.z; xt[c4*4+3][r] = vv.w;
        }
        __syncthreads();
        #pragma unroll
        for (int k = 0; k < 32; ++k) {
            float2 xv = *reinterpret_cast<const float2*>(&xt[k][lane * 2]);
            const float4* wr = reinterpret_cast<const float4*>(Wsh + (kc + k) * 32 + cg * 8);
            float4 w0 = wr[0];   // wave-uniform LDS address -> broadcast
            float4 w1 = wr[1];
            a00.x += xv.x * w0.x; a00.y += xv.x * w0.y; a00.z += xv.x * w0.z; a00.w += xv.x * w0.w;
            a01.x += xv.x * w1.x; a01.y += xv.x * w1.y; a01.z += xv.x * w1.z; a01.w += xv.x * w1.w;
            a10.x += xv.y * w0.x; a10.y += xv.y * w0.y; a10.z += xv.y * w0.z; a10.w += xv.y * w0.w;
            a11.x += xv.y * w1.x; a11.y += xv.y * w1.y; a11.z += xv.y * w1.z; a11.w += xv.y * w1.w;
        }
    }
    int rbase = row0 + lane * 2;
    #pragma unroll
    for (int j = 0; j < 2; ++j) {
        int row = rbase + j;
        if (row <= N) {   // row N (pad) gets zeros naturally from zero-staged xt
            float4 p0 = j ? a10 : a00;
            float4 p1 = j ? a11 : a01;
            __half2 h0 = __floats2half2_rn(p0.x, p0.y);
            __half2 h1 = __floats2half2_rn(p0.z, p0.w);
            __half2 h2 = __floats2half2_rn(p1.x, p1.y);
            __half2 h3 = __floats2half2_rn(p1.z, p1.w);
            uint4 st;
            st.x = *reinterpret_cast<unsigned int*>(&h0);
            st.y = *reinterpret_cast<unsigned int*>(&h1);
            st.z = *reinterpret_cast<unsigned int*>(&h2);
            st.w = *reinterpret_cast<unsigned int*>(&h3);
            *reinterpret_cast<uint4*>(h + (size_t)row * 32 + cg * 8) = st;
        }
    }
}

// binA: 512 threads, 4096 edges/block. Rank -> scan -> LDS stage (bucket-sorted)
// -> contiguous run writes into bucket-owned regions.
__global__ __launch_bounds__(512)
void k_binA(const int* __restrict__ src, const int* __restrict__ dst, int E,
            int* __restrict__ cursor, unsigned int* __restrict__ binned) {
    __shared__ int cnt[512];
    __shared__ int sc[512];
    __shared__ int lbase[512];
    __shared__ int gbs[512];
    __shared__ unsigned int stage[CHUNK];
    int tid = threadIdx.x;
    cnt[tid] = 0;
    __syncthreads();
    int base = (int)blockIdx.x * CHUNK;
    unsigned int pk[8];
    int rk[8];
    unsigned int mask = 0;
    #pragma unroll
    for (int i = 0; i < 2; ++i) {
        int e = base + i * 2048 + tid * 4;
        if (e + 3 < E) {
            int4 d4 = *reinterpret_cast<const int4*>(dst + e);
            int4 s4 = *reinterpret_cast<const int4*>(src + e);
            pk[i*4+0] = ((unsigned)d4.x << 16) | (unsigned)s4.x; rk[i*4+0] = atomicAdd(&cnt[d4.x >> 7], 1);
            pk[i*4+1] = ((unsigned)d4.y << 16) | (unsigned)s4.y; rk[i*4+1] = atomicAdd(&cnt[d4.y >> 7], 1);
            pk[i*4+2] = ((unsigned)d4.z << 16) | (unsigned)s4.z; rk[i*4+2] = atomicAdd(&cnt[d4.z >> 7], 1);
            pk[i*4+3] = ((unsigned)d4.w << 16) | (unsigned)s4.w; rk[i*4+3] = atomicAdd(&cnt[d4.w >> 7], 1);
            mask |= 0xFu << (i * 4);
        } else {
            for (int j = 0; j < 4; ++j) {
                int k = e + j;
                if (k < E) {
                    int d = dst[k], s = src[k];
                    pk[i*4+j] = ((unsigned)d << 16) | (unsigned)s;
                    rk[i*4+j] = atomicAdd(&cnt[d >> 7], 1);
                    mask |= 1u << (i * 4 + j);
                }
            }
        }
    }
    __syncthreads();
    int myc = cnt[tid];
    sc[tid] = myc;
    __syncthreads();
    for (int off = 1; off < 512; off <<= 1) {
        int v = (tid >= off) ? sc[tid - off] : 0;
        __syncthreads();
        sc[tid] += v;
        __syncthreads();
    }
    lbase[tid] = sc[tid] - myc;
    gbs[tid] = myc ? atomicAdd(&cursor[tid], myc) : 0;
    int nvalid = sc[511];
    __syncthreads();
    #pragma unroll
    for (int i = 0; i < 8; ++i) {
        if (mask & (1u << i)) {
            int b = pk[i] >> 23;
            stage[lbase[b] + rk[i]] = pk[i];
        }
    }
    __syncthreads();
    for (int i = tid; i < nvalid; i += 512) {
        unsigned int v = stage[i];
        int b = v >> 23;
        binned[(size_t)b * BCAP + gbs[b] + (i - lbase[b])] = v;
    }
}

// binB: one block per 128-node bucket. Single pass with rank recording.
__global__ __launch_bounds__(512)
void k_binB(const unsigned int* __restrict__ binned, const int* __restrict__ cursor,
            int* __restrict__ rowbeg, int* __restrict__ rowend, float* __restrict__ dinvg,
            unsigned short* __restrict__ csr, __half* __restrict__ hh, int N) {
    __shared__ int cnt[128];
    __shared__ int sc[128];
    __shared__ int excls[128];
    __shared__ float dv[128];
    int tid = threadIdx.x;
    int b = blockIdx.x;
    size_t ebase = (size_t)b * BCAP;
    int ne = cursor[b];
    if (tid < 128) cnt[tid] = 0;
    __syncthreads();
    unsigned int pk[16];
    int rk[16];
    #pragma unroll
    for (int ii = 0; ii < 16; ++ii) {
        int i = ii * 512 + tid;
        if (i < ne) {
            pk[ii] = binned[ebase + i];
            rk[ii] = atomicAdd(&cnt[(pk[ii] >> 16) & 127], 1);
        }
    }
    __syncthreads();
    int myc = 0, pcnt = 0;
    if (tid < 128) {
        myc = cnt[tid];
        pcnt = (myc + 1 + 15) & ~15;   // self + edges, padded to x16
        sc[tid] = pcnt;
    }
    __syncthreads();
    for (int off = 1; off < 128; off <<= 1) {
        int v = 0;
        if (tid < 128 && tid >= off) v = sc[tid - off];
        __syncthreads();
        if (tid < 128) sc[tid] += v;
        __syncthreads();
    }
    int cbase = b * CCAP;
    if (tid < 128) {
        int pexcl = sc[tid] - pcnt;
        excls[tid] = pexcl;
        int node = (b << 7) + tid;
        int rb = cbase + pexcl;
        float di = rsqrtf((float)(myc + 1));
        dv[tid] = di;
        if (node < N) {
            rowbeg[node] = rb;
            rowend[node] = rb + pcnt;
            dinvg[node] = di;
            csr[rb] = (unsigned short)node;   // self entry first
        }
    }
    __syncthreads();
    #pragma unroll
    for (int ii = 0; ii < 16; ++ii) {
        int i = ii * 512 + tid;
        if (i < ne) {
            int nl = (pk[ii] >> 16) & 127;
            csr[cbase + excls[nl] + 1 + rk[ii]] = (unsigned short)(pk[ii] & 0xFFFFu);
        }
    }
    __syncthreads();
    if (tid < 128) {   // fill pad slots with dummy node N (zero row)
        int pexcl = excls[tid];
        for (int p = pexcl + 1 + myc; p < pexcl + pcnt; ++p)
            csr[cbase + p] = (unsigned short)N;
    }
    __syncthreads();
    // scale h rows of this bucket by dinv (fp16 in place): 128 rows x 4 uint4
    uint4* h4 = reinterpret_cast<uint4*>(hh);
    size_t hbase = (size_t)(b << 7) * 4;
    {
        int nl = tid >> 2;
        if (((b << 7) + nl) < N) {
            uint4 v = h4[hbase + tid];
            float d = dv[nl];
            __half2* hv = reinterpret_cast<__half2*>(&v);
            #pragma unroll
            for (int t = 0; t < 4; ++t) {
                float2 f = __half22float2(hv[t]);
                hv[t] = __floats2half2_rn(f.x * d, f.y * d);
            }
            h4[hbase + tid] = v;
        }
    }
}

#define ACC8(A, V) do {                                             \
    const __half2* hv_ = reinterpret_cast<const __half2*>(&(V));    \
    float2 f0_ = __half22float2(hv_[0]);                            \
    float2 f1_ = __half22float2(hv_[1]);                            \
    float2 f2_ = __half22float2(hv_[2]);                            \
    float2 f3_ = __half22float2(hv_[3]);                            \
    (A)[0] += f0_.x; (A)[1] += f0_.y;                               \
    (A)[2] += f1_.x; (A)[3] += f1_.y;                               \
    (A)[4] += f2_.x; (A)[5] += f2_.y;                               \
    (A)[6] += f3_.x; (A)[7] += f3_.y;                               \
} while (0)

// agg layer1 + bias + relu + gemm2 + dinv pre-scale, fp16 gather payload.
// Full 64-entry chunk processed unconditionally (pad entries hit zero row N),
// 4 independent uint4 gathers in flight per iteration (MLP restore).
__global__ __launch_bounds__(THREADS)
void k_aggmm1(const __half* __restrict__ hp, const int* __restrict__ rowbeg,
              const int* __restrict__ rowend, const unsigned short* __restrict__ csr,
              const float* __restrict__ dinv, const float* __restrict__ b1,
              const float* __restrict__ W2, __half* __restrict__ hp2, int N) {
    int tid = threadIdx.x;
    int lane = tid & 63;
    int node = blockIdx.x * 4 + (tid >> 6);
    if (node > N) return;
    if (node == N) {   // dummy pad row of hp2: zeros
        if (lane < 4) reinterpret_cast<uint4*>(hp2 + (size_t)N * 32)[lane] =
            make_uint4(0u, 0u, 0u, 0u);
        return;
    }
    int j = lane >> 2, q = lane & 3;   // j: source slot in group of 16, q: 16B chunk
    int beg = rowbeg[node];
    int end = rowend[node];
    float acc[8], accB[8];
    #pragma unroll
    for (int t = 0; t < 8; ++t) { acc[t] = 0.f; accB[t] = 0.f; }
    const uint4* hp4 = reinterpret_cast<const uint4*>(hp);
    for (int base = beg; base < end; base += 64) {
        int idx = base + lane;
        int cv = (idx < end) ? (int)csr[idx] : N;   // oob lanes -> zero row N
        int s0 = __shfl(cv, j, 64);
        int s1 = __shfl(cv, 16 + j, 64);
        int s2 = __shfl(cv, 32 + j, 64);
        int s3 = __shfl(cv, 48 + j, 64);
        uint4 v0 = hp4[(size_t)s0 * 4 + q];
        uint4 v1 = hp4[(size_t)s1 * 4 + q];
        uint4 v2 = hp4[(size_t)s2 * 4 + q];
        uint4 v3 = hp4[(size_t)s3 * 4 + q];
        ACC8(acc, v0); ACC8(accB, v1); ACC8(acc, v2); ACC8(accB, v3);
    }
    #pragma unroll
    for (int t = 0; t < 8; ++t) acc[t] += accB[t];
    #pragma unroll
    for (int d = 4; d < 64; d <<= 1) {
        #pragma unroll
        for (int t = 0; t < 8; ++t) acc[t] += __shfl_xor(acc[t], d, 64);
    }
    // feature k lives on lane q=k>>3, register k&7
    int cp = lane & 31;
    float dd = dinv[node];
    float o0 = 0.f, o1 = 0.f;
    #pragma unroll
    for (int k = 0; k < 32; k += 2) {
        float t0 = __shfl(acc[k & 7], k >> 3, 64);
        float t1 = __shfl(acc[(k + 1) & 7], (k + 1) >> 3, 64);
        o0 += fmaxf(t0 * dd + b1[k], 0.f)     * W2[k * 32 + cp];
        o1 += fmaxf(t1 * dd + b1[k + 1], 0.f) * W2[(k + 1) * 32 + cp];
    }
    float o = (o0 + o1) * dd;   // pre-scale for layer-2 aggregation
    float onb = __shfl_xor(o, 1, 64);
    if (lane < 32 && !(cp & 1)) {
        __half2 p = __floats2half2_rn(o, onb);
        *reinterpret_cast<__half2*>(hp2 + (size_t)node * 32 + cp) = p;
    }
}

// agg layer2 + bias + relu + head, fp16 gather payload.
__global__ __launch_bounds__(THREADS)
void k_aggout(const __half* __restrict__ hp, const int* __restrict__ rowbeg,
              const int* __restrict__ rowend, const unsigned short* __restrict__ csr,
              const float* __restrict__ dinv, const float* __restrict__ b2,
              const float* __restrict__ Wo, const float* __restrict__ bo,
              float* __restrict__ out, int N) {
    int tid = threadIdx.x;
    int lane = tid & 63;
    int node = blockIdx.x * 4 + (tid >> 6);
    if (node >= N) return;
    int j = lane >> 2, q = lane & 3;
    int beg = rowbeg[node];
    int end = rowend[node];
    float acc[8], accB[8];
    #pragma unroll
    for (int t = 0; t < 8; ++t) { acc[t] = 0.f; accB[t] = 0.f; }
    const uint4* hp4 = reinterpret_cast<const uint4*>(hp);
    for (int base = beg; base < end; base += 64) {
        int idx = base + lane;
        int cv = (idx < end) ? (int)csr[idx] : N;
        int s0 = __shfl(cv, j, 64);
        int s1 = __shfl(cv, 16 + j, 64);
        int s2 = __shfl(cv, 32 + j, 64);
        int s3 = __shfl(cv, 48 + j, 64);
        uint4 v0 = hp4[(size_t)s0 * 4 + q];
        uint4 v1 = hp4[(size_t)s1 * 4 + q];
        uint4 v2 = hp4[(size_t)s2 * 4 + q];
        uint4 v3 = hp4[(size_t)s3 * 4 + q];
        ACC8(acc, v0); ACC8(accB, v1); ACC8(acc, v2); ACC8(accB, v3);
    }
    #pragma unroll
    for (int t = 0; t < 8; ++t) acc[t] += accB[t];
    #pragma unroll
    for (int d = 4; d < 64; d <<= 1) {
        #pragma unroll
        for (int t = 0; t < 8; ++t) acc[t] += __shfl_xor(acc[t], d, 64);
    }
    float dd = dinv[node];
    float o0 = bo[lane], o1 = 0.f;
    #pragma unroll
    for (int k = 0; k < 32; k += 2) {
        float t0 = __shfl(acc[k & 7], k >> 3, 64);
        float t1 = __shfl(acc[(k + 1) & 7], (k + 1) >> 3, 64);
        o0 += fmaxf(t0 * dd + b2[k], 0.f)     * Wo[k * 64 + lane];
        o1 += fmaxf(t1 * dd + b2[k + 1], 0.f) * Wo[(k + 1) * 64 + lane];
    }
    out[(size_t)node * 64 + lane] = o0 + o1;
}

extern "C" void kernel_launch(void* const* d_in, const int* in_sizes, int n_in,
                              void* d_out, int out_size, void* d_ws, size_t ws_size,
                              hipStream_t stream) {
    const float* x  = (const float*)d_in[0];
    const int*   ei = (const int*)d_in[1];
    const float* W1 = (const float*)d_in[2];
    const float* b1 = (const float*)d_in[3];
    const float* W2 = (const float*)d_in[4];
    const float* b2 = (const float*)d_in[5];
    const float* Wo = (const float*)d_in[6];
    const float* bo = (const float*)d_in[7];
    float* out = (float*)d_out;

    const int N = in_sizes[0] / 128;   // 50000
    const int E = in_sizes[1] / 2;     // 1600000
    const int* src = ei;
    const int* dst = ei + E;

    char* ws = (char*)d_ws;
    size_t off = 0;
    auto alloc = [&](size_t bytes) {
        void* p = ws + off;
        off += (bytes + 255) & ~(size_t)255;
        return p;
    };
    int*            cursor = (int*)           alloc(512 * 4);
    unsigned int*   binned = (unsigned int*)  alloc((size_t)NBUCK * BCAP * 4);
    int*            rowbeg = (int*)           alloc((size_t)N * 4);
    int*            rowend = (int*)           alloc((size_t)N * 4);
    float*          dinv   = (float*)         alloc((size_t)N * 4);
    unsigned short* csr    = (unsigned short*)alloc((size_t)NBUCK * CCAP * 2);
    __half*         bufAh  = (__half*)        alloc((size_t)(N + 1) * 32 * 2);
    __half*         bufBh  = (__half*)        alloc((size_t)(N + 1) * 32 * 2);

    const int nbinA  = (E + CHUNK - 1) / CHUNK;      // 391
    const int nGemm1 = (N + 1 + 127) / 128;          // 391 (covers pad row N)
    const int gAgg1  = (N + 1 + 3) / 4;              // covers node N (zero row)
    const int gAgg2  = (N + 3) / 4;

    hipMemsetAsync(cursor, 0, 512 * 4, stream);
    k_gemm1<<<nGemm1, 256, 0, stream>>>(x, W1, bufAh, N);
    k_binA<<<nbinA, 512, 0, stream>>>(src, dst, E, cursor, binned);
    k_binB<<<NBUCK, 512, 0, stream>>>(binned, cursor, rowbeg, rowend, dinv,
                                      csr, bufAh, N);
    k_aggmm1<<<gAgg1, THREADS, 0, stream>>>(bufAh, rowbeg, rowend, csr, dinv, b1,
                                            W2, bufBh, N);
    k_aggout<<<gAgg2, THREADS, 0, stream>>>(bufBh, rowbeg, rowend, csr, dinv, b2,
                                            Wo, bo, out, N);
}

// Round 3
// 201.384 us; speedup vs baseline: 1.1173x; 1.0616x over previous
//
#include <hip/hip_runtime.h>
#include <hip/hip_fp16.h>

#define CHUNK 4096        // edges per binA block
#define NBUCK 391         // buckets of 128 nodes (dst>>7)
#define BCAP  8192        // per-bucket edge capacity (mean 4096, 64 sigma slack)
#define CCAP  (BCAP+2048) // csr region capacity (edges + self + per-row pad to x16)

// gemm1: h = x @ W1 unscaled -> fp16. 128 rows/block; thread = 2 rows x 8 cols.
__global__ __launch_bounds__(256)
void k_gemm1(const float* __restrict__ x, const float* __restrict__ W,
             __half* __restrict__ h, int N) {
    __shared__ float Wsh[128 * 32];   // 16 KB
    __shared__ float xt[32][130];     // 16.3 KB
    int tid = threadIdx.x;
    int row0 = (int)blockIdx.x * 128;
    int lane = tid & 63;              // rows 2*lane, 2*lane+1
    int cg = tid >> 6;                // cols cg*8 .. cg*8+7
    for (int j = tid; j < 1024; j += 256)
        reinterpret_cast<float4*>(Wsh)[j] = reinterpret_cast<const float4*>(W)[j];
    const float4 z4 = make_float4(0.f, 0.f, 0.f, 0.f);
    float4 a00 = z4, a01 = z4, a10 = z4, a11 = z4;
    for (int kc = 0; kc < 128; kc += 32) {
        __syncthreads();
        #pragma unroll
        for (int i = 0; i < 4; ++i) {
            int f = i * 256 + tid;
            int r = f >> 3, c4 = f & 7;   // row 0..127, float4-col 0..7
            int gr = row0 + r;
            float4 vv = (gr < N)
                ? *reinterpret_cast<const float4*>(x + (size_t)gr * 128 + kc + c4 * 4)
                : z4;
            xt[c4*4+0][r] = vv.x; xt[c4*4+1][r] = vv.y;
            xt[c4*4+2][r] = vv.z; xt[c4*4+3][r] = vv.w;
        }
        __syncthreads();
        #pragma unroll
        for (int k = 0; k < 32; ++k) {
            float2 xv = *reinterpret_cast<const float2*>(&xt[k][lane * 2]);
            const float4* wr = reinterpret_cast<const float4*>(Wsh + (kc + k) * 32 + cg * 8);
            float4 w0 = wr[0];   // wave-uniform LDS address -> broadcast
            float4 w1 = wr[1];
            a00.x += xv.x * w0.x; a00.y += xv.x * w0.y; a00.z += xv.x * w0.z; a00.w += xv.x * w0.w;
            a01.x += xv.x * w1.x; a01.y += xv.x * w1.y; a01.z += xv.x * w1.z; a01.w += xv.x * w1.w;
            a10.x += xv.y * w0.x; a10.y += xv.y * w0.y; a10.z += xv.y * w0.z; a10.w += xv.y * w0.w;
            a11.x += xv.y * w1.x; a11.y += xv.y * w1.y; a11.z += xv.y * w1.z; a11.w += xv.y * w1.w;
        }
    }
    int rbase = row0 + lane * 2;
    #pragma unroll
    for (int j = 0; j < 2; ++j) {
        int row = rbase + j;
        if (row <= N) {   // row N (pad) gets zeros naturally from zero-staged xt
            float4 p0 = j ? a10 : a00;
            float4 p1 = j ? a11 : a01;
            __half2 h0 = __floats2half2_rn(p0.x, p0.y);
            __half2 h1 = __floats2half2_rn(p0.z, p0.w);
            __half2 h2 = __floats2half2_rn(p1.x, p1.y);
            __half2 h3 = __floats2half2_rn(p1.z, p1.w);
            uint4 st;
            st.x = *reinterpret_cast<unsigned int*>(&h0);
            st.y = *reinterpret_cast<unsigned int*>(&h1);
            st.z = *reinterpret_cast<unsigned int*>(&h2);
            st.w = *reinterpret_cast<unsigned int*>(&h3);
            *reinterpret_cast<uint4*>(h + (size_t)row * 32 + cg * 8) = st;
        }
    }
}

// binA: 512 threads, 4096 edges/block. Rank -> scan -> LDS stage (bucket-sorted)
// -> contiguous run writes into bucket-owned regions.
__global__ __launch_bounds__(512)
void k_binA(const int* __restrict__ src, const int* __restrict__ dst, int E,
            int* __restrict__ cursor, unsigned int* __restrict__ binned) {
    __shared__ int cnt[512];
    __shared__ int sc[512];
    __shared__ int lbase[512];
    __shared__ int gbs[512];
    __shared__ unsigned int stage[CHUNK];
    int tid = threadIdx.x;
    cnt[tid] = 0;
    __syncthreads();
    int base = (int)blockIdx.x * CHUNK;
    unsigned int pk[8];
    int rk[8];
    unsigned int mask = 0;
    #pragma unroll
    for (int i = 0; i < 2; ++i) {
        int e = base + i * 2048 + tid * 4;
        if (e + 3 < E) {
            int4 d4 = *reinterpret_cast<const int4*>(dst + e);
            int4 s4 = *reinterpret_cast<const int4*>(src + e);
            pk[i*4+0] = ((unsigned)d4.x << 16) | (unsigned)s4.x; rk[i*4+0] = atomicAdd(&cnt[d4.x >> 7], 1);
            pk[i*4+1] = ((unsigned)d4.y << 16) | (unsigned)s4.y; rk[i*4+1] = atomicAdd(&cnt[d4.y >> 7], 1);
            pk[i*4+2] = ((unsigned)d4.z << 16) | (unsigned)s4.z; rk[i*4+2] = atomicAdd(&cnt[d4.z >> 7], 1);
            pk[i*4+3] = ((unsigned)d4.w << 16) | (unsigned)s4.w; rk[i*4+3] = atomicAdd(&cnt[d4.w >> 7], 1);
            mask |= 0xFu << (i * 4);
        } else {
            for (int j = 0; j < 4; ++j) {
                int k = e + j;
                if (k < E) {
                    int d = dst[k], s = src[k];
                    pk[i*4+j] = ((unsigned)d << 16) | (unsigned)s;
                    rk[i*4+j] = atomicAdd(&cnt[d >> 7], 1);
                    mask |= 1u << (i * 4 + j);
                }
            }
        }
    }
    __syncthreads();
    int myc = cnt[tid];
    sc[tid] = myc;
    __syncthreads();
    for (int off = 1; off < 512; off <<= 1) {
        int v = (tid >= off) ? sc[tid - off] : 0;
        __syncthreads();
        sc[tid] += v;
        __syncthreads();
    }
    lbase[tid] = sc[tid] - myc;
    gbs[tid] = myc ? atomicAdd(&cursor[tid], myc) : 0;
    int nvalid = sc[511];
    __syncthreads();
    #pragma unroll
    for (int i = 0; i < 8; ++i) {
        if (mask & (1u << i)) {
            int b = pk[i] >> 23;
            stage[lbase[b] + rk[i]] = pk[i];
        }
    }
    __syncthreads();
    for (int i = tid; i < nvalid; i += 512) {
        unsigned int v = stage[i];
        int b = v >> 23;
        binned[(size_t)b * BCAP + gbs[b] + (i - lbase[b])] = v;
    }
}

// binB: one block per 128-node bucket. Single pass with rank recording.
// rowend now stores the EXACT end (self + edges, no pad): agg kernels skip pads.
__global__ __launch_bounds__(512)
void k_binB(const unsigned int* __restrict__ binned, const int* __restrict__ cursor,
            int* __restrict__ rowbeg, int* __restrict__ rowend, float* __restrict__ dinvg,
            unsigned short* __restrict__ csr, __half* __restrict__ hh, int N) {
    __shared__ int cnt[128];
    __shared__ int sc[128];
    __shared__ int excls[128];
    __shared__ float dv[128];
    int tid = threadIdx.x;
    int b = blockIdx.x;
    size_t ebase = (size_t)b * BCAP;
    int ne = cursor[b];
    if (tid < 128) cnt[tid] = 0;
    __syncthreads();
    unsigned int pk[16];
    int rk[16];
    #pragma unroll
    for (int ii = 0; ii < 16; ++ii) {
        int i = ii * 512 + tid;
        if (i < ne) {
            pk[ii] = binned[ebase + i];
            rk[ii] = atomicAdd(&cnt[(pk[ii] >> 16) & 127], 1);
        }
    }
    __syncthreads();
    int myc = 0, pcnt = 0;
    if (tid < 128) {
        myc = cnt[tid];
        pcnt = (myc + 1 + 15) & ~15;   // self + edges, padded to x16 (region layout)
        sc[tid] = pcnt;
    }
    __syncthreads();
    for (int off = 1; off < 128; off <<= 1) {
        int v = 0;
        if (tid < 128 && tid >= off) v = sc[tid - off];
        __syncthreads();
        if (tid < 128) sc[tid] += v;
        __syncthreads();
    }
    int cbase = b * CCAP;
    if (tid < 128) {
        int pexcl = sc[tid] - pcnt;
        excls[tid] = pexcl;
        int node = (b << 7) + tid;
        int rb = cbase + pexcl;
        float di = rsqrtf((float)(myc + 1));
        dv[tid] = di;
        if (node < N) {
            rowbeg[node] = rb;
            rowend[node] = rb + 1 + myc;   // EXACT end (pads excluded)
            dinvg[node] = di;
            csr[rb] = (unsigned short)node;   // self entry first
        }
    }
    __syncthreads();
    #pragma unroll
    for (int ii = 0; ii < 16; ++ii) {
        int i = ii * 512 + tid;
        if (i < ne) {
            int nl = (pk[ii] >> 16) & 127;
            csr[cbase + excls[nl] + 1 + rk[ii]] = (unsigned short)(pk[ii] & 0xFFFFu);
        }
    }
    __syncthreads();
    if (tid < 128) {   // fill pad slots with dummy node N (zero row) -- chunk overreads hit these
        int pexcl = excls[tid];
        for (int p = pexcl + 1 + myc; p < pexcl + pcnt; ++p)
            csr[cbase + p] = (unsigned short)N;
    }
    __syncthreads();
    // scale h rows of this bucket by dinv (fp16 in place): 128 rows x 4 uint4
    uint4* h4 = reinterpret_cast<uint4*>(hh);
    size_t hbase = (size_t)(b << 7) * 4;
    {
        int nl = tid >> 2;
        if (((b << 7) + nl) < N) {
            uint4 v = h4[hbase + tid];
            float d = dv[nl];
            __half2* hv = reinterpret_cast<__half2*>(&v);
            #pragma unroll
            for (int t = 0; t < 4; ++t) {
                float2 f = __half22float2(hv[t]);
                hv[t] = __floats2half2_rn(f.x * d, f.y * d);
            }
            h4[hbase + tid] = v;
        }
    }
}

#define ACC8(A, V) do {                                             \
    const __half2* hv_ = reinterpret_cast<const __half2*>(&(V));    \
    float2 f0_ = __half22float2(hv_[0]);                            \
    float2 f1_ = __half22float2(hv_[1]);                            \
    float2 f2_ = __half22float2(hv_[2]);                            \
    float2 f3_ = __half22float2(hv_[3]);                            \
    (A)[0] += f0_.x; (A)[1] += f0_.y;                               \
    (A)[2] += f1_.x; (A)[3] += f1_.y;                               \
    (A)[4] += f2_.x; (A)[5] += f2_.y;                               \
    (A)[6] += f3_.x; (A)[7] += f3_.y;                               \
} while (0)

// agg layer1 + bias + relu + gemm2 + dinv pre-scale.
// 32 nodes/block, 4 lanes per node (q = 16B chunk): each group walks its own row
// -> per-lane per-feature partials, NO cross-lane reduce. 2-way row split across
// wave pairs for occupancy; partials combine via ds_add into aggT[32][33].
// Epilogue: block-level LDS matvec (broadcast reads), no shfl chains.
__global__ __launch_bounds__(256)
void k_aggmm1(const __half* __restrict__ hp, const int* __restrict__ rowbeg,
              const int* __restrict__ rowend, const unsigned short* __restrict__ csr,
              const float* __restrict__ dinv, const float* __restrict__ b1,
              const float* __restrict__ W2, __half* __restrict__ hp2, int N) {
    __shared__ float aggT[32][33];    // [feature][node], pitch 33
    __shared__ float W2sh[32 * 32];   // 4 KB
    int tid = threadIdx.x;
    int lane = tid & 63;
    int w = tid >> 6;
    int g = lane >> 2, q = lane & 3;
    int h = w & 1;                    // row-split half
    int node_loc = (w >> 1) * 16 + g; // 0..31
    int node = (int)blockIdx.x * 32 + node_loc;

    for (int i = tid; i < 1056; i += 256) (&aggT[0][0])[i] = 0.f;
    for (int i = tid; i < 256; i += 256)
        reinterpret_cast<float4*>(W2sh)[i] = reinterpret_cast<const float4*>(W2)[i];
    __syncthreads();

    float acc[8], accB[8];
    #pragma unroll
    for (int t = 0; t < 8; ++t) { acc[t] = 0.f; accB[t] = 0.f; }
    int beg = 0, endx = 0;
    if (node < N) { beg = rowbeg[node]; endx = rowend[node]; }
    const uint4* hp4 = reinterpret_cast<const uint4*>(hp);
    for (int t = beg + 4 * h; t < endx; t += 8) {
        ushort4 s4 = *reinterpret_cast<const ushort4*>(csr + t);  // overread -> pads (=N, zero row)
        unsigned int i0 = (unsigned int)s4.x * 4u + q;
        unsigned int i1 = (unsigned int)s4.y * 4u + q;
        unsigned int i2 = (unsigned int)s4.z * 4u + q;
        unsigned int i3 = (unsigned int)s4.w * 4u + q;
        uint4 v0 = hp4[i0];
        uint4 v1 = hp4[i1];
        uint4 v2 = hp4[i2];
        uint4 v3 = hp4[i3];
        ACC8(acc, v0); ACC8(accB, v1); ACC8(acc, v2); ACC8(accB, v3);
    }
    #pragma unroll
    for (int j2 = 0; j2 < 8; ++j2)
        atomicAdd(&aggT[q * 8 + j2][node_loc], acc[j2] + accB[j2]);
    __syncthreads();

    // epilogue: 8 threads/node, 4 outcols each
    int nl2 = tid >> 3;               // 0..31
    int cgrp = tid & 7;               // cols cgrp*4..+3
    int onode = (int)blockIdx.x * 32 + nl2;
    float dd = (onode < N) ? dinv[onode] : 0.f;
    float o0 = 0.f, o1 = 0.f, o2 = 0.f, o3 = 0.f;
    #pragma unroll
    for (int k = 0; k < 32; ++k) {
        float yk = fmaxf(aggT[k][nl2] * dd + b1[k], 0.f);
        float4 wv = *reinterpret_cast<const float4*>(&W2sh[k * 32 + cgrp * 4]);
        o0 += yk * wv.x; o1 += yk * wv.y; o2 += yk * wv.z; o3 += yk * wv.w;
    }
    if (onode <= N) {   // node N: dd=0 -> stores zeros (pad row for layer-2 gathers)
        __half2 pa = __floats2half2_rn(o0 * dd, o1 * dd);
        __half2 pb = __floats2half2_rn(o2 * dd, o3 * dd);
        uint2 st;
        st.x = *reinterpret_cast<unsigned int*>(&pa);
        st.y = *reinterpret_cast<unsigned int*>(&pb);
        *reinterpret_cast<uint2*>(hp2 + (size_t)onode * 32 + cgrp * 4) = st;
    }
}

// agg layer2 + bias + relu + head (64 outcols). Same structure as k_aggmm1.
__global__ __launch_bounds__(256)
void k_aggout(const __half* __restrict__ hp, const int* __restrict__ rowbeg,
              const int* __restrict__ rowend, const unsigned short* __restrict__ csr,
              const float* __restrict__ dinv, const float* __restrict__ b2,
              const float* __restrict__ Wo, const float* __restrict__ bo,
              float* __restrict__ out, int N) {
    __shared__ float aggT[32][33];
    __shared__ float Wosh[32 * 64];   // 8 KB
    int tid = threadIdx.x;
    int lane = tid & 63;
    int w = tid >> 6;
    int g = lane >> 2, q = lane & 3;
    int h = w & 1;
    int node_loc = (w >> 1) * 16 + g;
    int node = (int)blockIdx.x * 32 + node_loc;

    for (int i = tid; i < 1056; i += 256) (&aggT[0][0])[i] = 0.f;
    for (int i = tid; i < 512; i += 256)
        reinterpret_cast<float4*>(Wosh)[i] = reinterpret_cast<const float4*>(Wo)[i];
    __syncthreads();

    float acc[8], accB[8];
    #pragma unroll
    for (int t = 0; t < 8; ++t) { acc[t] = 0.f; accB[t] = 0.f; }
    int beg = 0, endx = 0;
    if (node < N) { beg = rowbeg[node]; endx = rowend[node]; }
    const uint4* hp4 = reinterpret_cast<const uint4*>(hp);
    for (int t = beg + 4 * h; t < endx; t += 8) {
        ushort4 s4 = *reinterpret_cast<const ushort4*>(csr + t);
        unsigned int i0 = (unsigned int)s4.x * 4u + q;
        unsigned int i1 = (unsigned int)s4.y * 4u + q;
        unsigned int i2 = (unsigned int)s4.z * 4u + q;
        unsigned int i3 = (unsigned int)s4.w * 4u + q;
        uint4 v0 = hp4[i0];
        uint4 v1 = hp4[i1];
        uint4 v2 = hp4[i2];
        uint4 v3 = hp4[i3];
        ACC8(acc, v0); ACC8(accB, v1); ACC8(acc, v2); ACC8(accB, v3);
    }
    #pragma unroll
    for (int j2 = 0; j2 < 8; ++j2)
        atomicAdd(&aggT[q * 8 + j2][node_loc], acc[j2] + accB[j2]);
    __syncthreads();

    // epilogue: 8 threads/node, 8 outcols each
    int nl2 = tid >> 3;
    int cgrp = tid & 7;               // cols cgrp*8..+7
    int onode = (int)blockIdx.x * 32 + nl2;
    float dd = (onode < N) ? dinv[onode] : 0.f;
    float o[8];
    #pragma unroll
    for (int i = 0; i < 8; ++i) o[i] = 0.f;
    #pragma unroll
    for (int k = 0; k < 32; ++k) {
        float yk = fmaxf(aggT[k][nl2] * dd + b2[k], 0.f);
        float4 wa = *reinterpret_cast<const float4*>(&Wosh[k * 64 + cgrp * 8]);
        float4 wb = *reinterpret_cast<const float4*>(&Wosh[k * 64 + cgrp * 8 + 4]);
        o[0] += yk * wa.x; o[1] += yk * wa.y; o[2] += yk * wa.z; o[3] += yk * wa.w;
        o[4] += yk * wb.x; o[5] += yk * wb.y; o[6] += yk * wb.z; o[7] += yk * wb.w;
    }
    if (onode < N) {
        float4 ba = *reinterpret_cast<const float4*>(bo + cgrp * 8);
        float4 bb = *reinterpret_cast<const float4*>(bo + cgrp * 8 + 4);
        float4 s0 = make_float4(o[0] + ba.x, o[1] + ba.y, o[2] + ba.z, o[3] + ba.w);
        float4 s1 = make_float4(o[4] + bb.x, o[5] + bb.y, o[6] + bb.z, o[7] + bb.w);
        float4* op = reinterpret_cast<float4*>(out + (size_t)onode * 64 + cgrp * 8);
        op[0] = s0;
        op[1] = s1;
    }
}

extern "C" void kernel_launch(void* const* d_in, const int* in_sizes, int n_in,
                              void* d_out, int out_size, void* d_ws, size_t ws_size,
                              hipStream_t stream) {
    const float* x  = (const float*)d_in[0];
    const int*   ei = (const int*)d_in[1];
    const float* W1 = (const float*)d_in[2];
    const float* b1 = (const float*)d_in[3];
    const float* W2 = (const float*)d_in[4];
    const float* b2 = (const float*)d_in[5];
    const float* Wo = (const float*)d_in[6];
    const float* bo = (const float*)d_in[7];
    float* out = (float*)d_out;

    const int N = in_sizes[0] / 128;   // 50000
    const int E = in_sizes[1] / 2;     // 1600000
    const int* src = ei;
    const int* dst = ei + E;

    char* ws = (char*)d_ws;
    size_t off = 0;
    auto alloc = [&](size_t bytes) {
        void* p = ws + off;
        off += (bytes + 255) & ~(size_t)255;
        return p;
    };
    int*            cursor = (int*)           alloc(512 * 4);
    unsigned int*   binned = (unsigned int*)  alloc((size_t)NBUCK * BCAP * 4);
    int*            rowbeg = (int*)           alloc((size_t)N * 4);
    int*            rowend = (int*)           alloc((size_t)N * 4);
    float*          dinv   = (float*)         alloc((size_t)N * 4);
    unsigned short* csr    = (unsigned short*)alloc((size_t)NBUCK * CCAP * 2);
    __half*         bufAh  = (__half*)        alloc((size_t)(N + 1) * 32 * 2);
    __half*         bufBh  = (__half*)        alloc((size_t)(N + 1) * 32 * 2);

    const int nbinA  = (E + CHUNK - 1) / CHUNK;      // 391
    const int nGemm1 = (N + 1 + 127) / 128;          // 391 (covers pad row N)
    const int gAgg1  = (N + 1 + 31) / 32;            // covers pad node N
    const int gAgg2  = (N + 31) / 32;

    hipMemsetAsync(cursor, 0, 512 * 4, stream);
    k_gemm1<<<nGemm1, 256, 0, stream>>>(x, W1, bufAh, N);
    k_binA<<<nbinA, 512, 0, stream>>>(src, dst, E, cursor, binned);
    k_binB<<<NBUCK, 512, 0, stream>>>(binned, cursor, rowbeg, rowend, dinv,
                                      csr, bufAh, N);
    k_aggmm1<<<gAgg1, 256, 0, stream>>>(bufAh, rowbeg, rowend, csr, dinv, b1,
                                        W2, bufBh, N);
    k_aggout<<<gAgg2, 256, 0, stream>>>(bufBh, rowbeg, rowend, csr, dinv, b2,
                                        Wo, bo, out, N);
}

// Round 4
// 201.104 us; speedup vs baseline: 1.1188x; 1.0014x over previous
//
#include <hip/hip_runtime.h>
#include <hip/hip_fp16.h>

#define CHUNK 4096        // edges per binA block
#define NBUCK 391         // buckets of 128 nodes (dst>>7)
#define BCAP  8192        // per-bucket edge capacity (mean 4096, 64 sigma slack)
#define CCAP  (BCAP+2048) // csr region capacity (edges + self + per-row pad to x16)
#define NGEMM 196         // gemm tiles of 256 rows (covers N+1 = 50001)

// Fused front kernel: gemm1 (x@W1 -> fp16) and binA (edge bucketing) are
// data-independent; one dispatch with interleaved block types overlaps them
// (cross-stream events are forbidden under graph capture).
union FrontSmem {
    struct { float Wsh[128 * 32]; float xt[32][258]; } g;   // 49.4 KB
    struct { int cnt[512]; int sc[512]; int lbase[512]; int gbs[512];
             unsigned int stage[CHUNK]; } a;                 // 24 KB
};

__global__ __launch_bounds__(512)
void k_front(const float* __restrict__ x, const float* __restrict__ W,
             __half* __restrict__ h, int N,
             const int* __restrict__ src, const int* __restrict__ dst, int E,
             int* __restrict__ cursor, unsigned int* __restrict__ binned) {
    __shared__ FrontSmem sm;
    int bid = (int)blockIdx.x;
    int tid = threadIdx.x;
    int g3 = bid / 3;
    bool isg = (bid % 3 == 0) && (g3 < NGEMM);

    if (isg) {
        // ---- gemm path: 256 rows/block, 512 threads = 128 row-pairs x 4 colgroups
        float* Wsh = sm.g.Wsh;
        int row0 = g3 * 256;
        int p = tid & 127;            // row pair: rows 2p, 2p+1
        int c8 = tid >> 7;            // col group: cols c8*8..+7
        for (int j = tid; j < 1024; j += 512)
            reinterpret_cast<float4*>(Wsh)[j] = reinterpret_cast<const float4*>(W)[j];
        const float4 z4 = make_float4(0.f, 0.f, 0.f, 0.f);
        float4 a00 = z4, a01 = z4, a10 = z4, a11 = z4;
        for (int kc = 0; kc < 128; kc += 32) {
            __syncthreads();
            #pragma unroll
            for (int i = 0; i < 4; ++i) {
                int f = i * 512 + tid;
                int r = f >> 3, c4 = f & 7;   // row 0..255, float4-col 0..7
                int gr = row0 + r;
                float4 vv = (gr < N)
                    ? *reinterpret_cast<const float4*>(x + (size_t)gr * 128 + kc + c4 * 4)
                    : z4;
                sm.g.xt[c4*4+0][r] = vv.x; sm.g.xt[c4*4+1][r] = vv.y;
                sm.g.xt[c4*4+2][r] = vv.z; sm.g.xt[c4*4+3][r] = vv.w;
            }
            __syncthreads();
            #pragma unroll
            for (int k = 0; k < 32; ++k) {
                float2 xv = *reinterpret_cast<const float2*>(&sm.g.xt[k][p * 2]);
                const float4* wr = reinterpret_cast<const float4*>(Wsh + (kc + k) * 32 + c8 * 8);
                float4 w0 = wr[0];   // wave-uniform LDS address -> broadcast
                float4 w1 = wr[1];
                a00.x += xv.x * w0.x; a00.y += xv.x * w0.y; a00.z += xv.x * w0.z; a00.w += xv.x * w0.w;
                a01.x += xv.x * w1.x; a01.y += xv.x * w1.y; a01.z += xv.x * w1.z; a01.w += xv.x * w1.w;
                a10.x += xv.y * w0.x; a10.y += xv.y * w0.y; a10.z += xv.y * w0.z; a10.w += xv.y * w0.w;
                a11.x += xv.y * w1.x; a11.y += xv.y * w1.y; a11.z += xv.y * w1.z; a11.w += xv.y * w1.w;
            }
        }
        int rbase = row0 + p * 2;
        #pragma unroll
        for (int j = 0; j < 2; ++j) {
            int row = rbase + j;
            if (row <= N) {   // row N (pad) gets zeros naturally from zero-staged xt
                float4 p0 = j ? a10 : a00;
                float4 p1 = j ? a11 : a01;
                __half2 h0 = __floats2half2_rn(p0.x, p0.y);
                __half2 h1 = __floats2half2_rn(p0.z, p0.w);
                __half2 h2 = __floats2half2_rn(p1.x, p1.y);
                __half2 h3 = __floats2half2_rn(p1.z, p1.w);
                uint4 st;
                st.x = *reinterpret_cast<unsigned int*>(&h0);
                st.y = *reinterpret_cast<unsigned int*>(&h1);
                st.z = *reinterpret_cast<unsigned int*>(&h2);
                st.w = *reinterpret_cast<unsigned int*>(&h3);
                *reinterpret_cast<uint4*>(h + (size_t)row * 32 + c8 * 8) = st;
            }
        }
        return;
    }

    // ---- binA path: rank -> scan -> LDS stage (bucket-sorted) -> run writes
    int abid = bid - min(NGEMM, (bid + 2) / 3);
    int* cnt = sm.a.cnt;
    int* sc = sm.a.sc;
    int* lbase = sm.a.lbase;
    int* gbs = sm.a.gbs;
    unsigned int* stage = sm.a.stage;
    cnt[tid] = 0;
    __syncthreads();
    int base = abid * CHUNK;
    unsigned int pk[8];
    int rk[8];
    unsigned int mask = 0;
    #pragma unroll
    for (int i = 0; i < 2; ++i) {
        int e = base + i * 2048 + tid * 4;
        if (e + 3 < E) {
            int4 d4 = *reinterpret_cast<const int4*>(dst + e);
            int4 s4 = *reinterpret_cast<const int4*>(src + e);
            pk[i*4+0] = ((unsigned)d4.x << 16) | (unsigned)s4.x; rk[i*4+0] = atomicAdd(&cnt[d4.x >> 7], 1);
            pk[i*4+1] = ((unsigned)d4.y << 16) | (unsigned)s4.y; rk[i*4+1] = atomicAdd(&cnt[d4.y >> 7], 1);
            pk[i*4+2] = ((unsigned)d4.z << 16) | (unsigned)s4.z; rk[i*4+2] = atomicAdd(&cnt[d4.z >> 7], 1);
            pk[i*4+3] = ((unsigned)d4.w << 16) | (unsigned)s4.w; rk[i*4+3] = atomicAdd(&cnt[d4.w >> 7], 1);
            mask |= 0xFu << (i * 4);
        } else {
            for (int j = 0; j < 4; ++j) {
                int k = e + j;
                if (k < E) {
                    int d = dst[k], s = src[k];
                    pk[i*4+j] = ((unsigned)d << 16) | (unsigned)s;
                    rk[i*4+j] = atomicAdd(&cnt[d >> 7], 1);
                    mask |= 1u << (i * 4 + j);
                }
            }
        }
    }
    __syncthreads();
    int myc = cnt[tid];
    sc[tid] = myc;
    __syncthreads();
    for (int off = 1; off < 512; off <<= 1) {
        int v = (tid >= off) ? sc[tid - off] : 0;
        __syncthreads();
        sc[tid] += v;
        __syncthreads();
    }
    lbase[tid] = sc[tid] - myc;
    gbs[tid] = myc ? atomicAdd(&cursor[tid], myc) : 0;
    int nvalid = sc[511];
    __syncthreads();
    #pragma unroll
    for (int i = 0; i < 8; ++i) {
        if (mask & (1u << i)) {
            int b = pk[i] >> 23;
            stage[lbase[b] + rk[i]] = pk[i];
        }
    }
    __syncthreads();
    for (int i = tid; i < nvalid; i += 512) {
        unsigned int v = stage[i];
        int b = v >> 23;
        binned[(size_t)b * BCAP + gbs[b] + (i - lbase[b])] = v;
    }
}

// binB: one block per 128-node bucket. Single pass with rank recording.
// rowend stores the EXACT end (self + edges, no pad): agg kernels skip pads.
__global__ __launch_bounds__(512)
void k_binB(const unsigned int* __restrict__ binned, const int* __restrict__ cursor,
            int* __restrict__ rowbeg, int* __restrict__ rowend, float* __restrict__ dinvg,
            unsigned short* __restrict__ csr, __half* __restrict__ hh, int N) {
    __shared__ int cnt[128];
    __shared__ int sc[128];
    __shared__ int excls[128];
    __shared__ float dv[128];
    int tid = threadIdx.x;
    int b = blockIdx.x;
    size_t ebase = (size_t)b * BCAP;
    int ne = cursor[b];
    if (tid < 128) cnt[tid] = 0;
    __syncthreads();
    unsigned int pk[16];
    int rk[16];
    #pragma unroll
    for (int ii = 0; ii < 16; ++ii) {
        int i = ii * 512 + tid;
        if (i < ne) {
            pk[ii] = binned[ebase + i];
            rk[ii] = atomicAdd(&cnt[(pk[ii] >> 16) & 127], 1);
        }
    }
    __syncthreads();
    int myc = 0, pcnt = 0;
    if (tid < 128) {
        myc = cnt[tid];
        pcnt = (myc + 1 + 15) & ~15;   // self + edges, padded to x16 (region layout)
        sc[tid] = pcnt;
    }
    __syncthreads();
    for (int off = 1; off < 128; off <<= 1) {
        int v = 0;
        if (tid < 128 && tid >= off) v = sc[tid - off];
        __syncthreads();
        if (tid < 128) sc[tid] += v;
        __syncthreads();
    }
    int cbase = b * CCAP;
    if (tid < 128) {
        int pexcl = sc[tid] - pcnt;
        excls[tid] = pexcl;
        int node = (b << 7) + tid;
        int rb = cbase + pexcl;
        float di = rsqrtf((float)(myc + 1));
        dv[tid] = di;
        if (node < N) {
            rowbeg[node] = rb;
            rowend[node] = rb + 1 + myc;   // EXACT end (pads excluded)
            dinvg[node] = di;
            csr[rb] = (unsigned short)node;   // self entry first
        }
    }
    __syncthreads();
    #pragma unroll
    for (int ii = 0; ii < 16; ++ii) {
        int i = ii * 512 + tid;
        if (i < ne) {
            int nl = (pk[ii] >> 16) & 127;
            csr[cbase + excls[nl] + 1 + rk[ii]] = (unsigned short)(pk[ii] & 0xFFFFu);
        }
    }
    __syncthreads();
    if (tid < 128) {   // fill pad slots with dummy node N (zero row) -- chunk overreads hit these
        int pexcl = excls[tid];
        for (int p = pexcl + 1 + myc; p < pexcl + pcnt; ++p)
            csr[cbase + p] = (unsigned short)N;
    }
    __syncthreads();
    // scale h rows of this bucket by dinv (fp16 in place): 128 rows x 4 uint4
    uint4* h4 = reinterpret_cast<uint4*>(hh);
    size_t hbase = (size_t)(b << 7) * 4;
    {
        int nl = tid >> 2;
        if (((b << 7) + nl) < N) {
            uint4 v = h4[hbase + tid];
            float d = dv[nl];
            __half2* hv = reinterpret_cast<__half2*>(&v);
            #pragma unroll
            for (int t = 0; t < 4; ++t) {
                float2 f = __half22float2(hv[t]);
                hv[t] = __floats2half2_rn(f.x * d, f.y * d);
            }
            h4[hbase + tid] = v;
        }
    }
}

// fp16 -> fp32 accumulate in ONE instruction per feature: v_fma_mix_f32
// acc = f16(lo/hi of U) * 1.0f + acc   (exact fp32 accumulate, halves VALU issue)
#define MIXLO(ACC, U) asm("v_fma_mix_f32 %0, %1, 1.0, %0 op_sel:[0,0,0] op_sel_hi:[1,0,0]" : "+v"(ACC) : "v"(U))
#define MIXHI(ACC, U) asm("v_fma_mix_f32 %0, %1, 1.0, %0 op_sel:[1,0,0] op_sel_hi:[1,0,0]" : "+v"(ACC) : "v"(U))
#define ACC8M(A, V) do {            \
    MIXLO((A)[0], (V).x); MIXHI((A)[1], (V).x); \
    MIXLO((A)[2], (V).y); MIXHI((A)[3], (V).y); \
    MIXLO((A)[4], (V).z); MIXHI((A)[5], (V).z); \
    MIXLO((A)[6], (V).w); MIXHI((A)[7], (V).w); \
} while (0)

// agg layer1 + bias + relu + gemm2 + dinv pre-scale.
// 32 nodes/block, 4 lanes per node: per-lane per-feature partials, no cross-lane
// reduce; partials combine via LDS atomics into aggT; block-level LDS matvec.
__global__ __launch_bounds__(256)
void k_aggmm1(const __half* __restrict__ hp, const int* __restrict__ rowbeg,
              const int* __restrict__ rowend, const unsigned short* __restrict__ csr,
              const float* __restrict__ dinv, const float* __restrict__ b1,
              const float* __restrict__ W2, __half* __restrict__ hp2, int N) {
    __shared__ float aggT[32][33];    // [feature][node], pitch 33
    __shared__ float W2sh[32 * 32];   // 4 KB
    int tid = threadIdx.x;
    int lane = tid & 63;
    int w = tid >> 6;
    int g = lane >> 2, q = lane & 3;
    int h = w & 1;                    // row-split half
    int node_loc = (w >> 1) * 16 + g; // 0..31
    int node = (int)blockIdx.x * 32 + node_loc;

    for (int i = tid; i < 1056; i += 256) (&aggT[0][0])[i] = 0.f;
    for (int i = tid; i < 256; i += 256)
        reinterpret_cast<float4*>(W2sh)[i] = reinterpret_cast<const float4*>(W2)[i];
    __syncthreads();

    float acc[8], accB[8];
    #pragma unroll
    for (int t = 0; t < 8; ++t) { acc[t] = 0.f; accB[t] = 0.f; }
    int beg = 0, endx = 0;
    if (node < N) { beg = rowbeg[node]; endx = rowend[node]; }
    const uint4* hp4 = reinterpret_cast<const uint4*>(hp);
    for (int t = beg + 4 * h; t < endx; t += 8) {
        ushort4 s4 = *reinterpret_cast<const ushort4*>(csr + t);  // overread -> pads (=N, zero row)
        unsigned int i0 = (unsigned int)s4.x * 4u + q;
        unsigned int i1 = (unsigned int)s4.y * 4u + q;
        unsigned int i2 = (unsigned int)s4.z * 4u + q;
        unsigned int i3 = (unsigned int)s4.w * 4u + q;
        uint4 v0 = hp4[i0];
        uint4 v1 = hp4[i1];
        uint4 v2 = hp4[i2];
        uint4 v3 = hp4[i3];
        ACC8M(acc, v0); ACC8M(accB, v1); ACC8M(acc, v2); ACC8M(accB, v3);
    }
    #pragma unroll
    for (int j2 = 0; j2 < 8; ++j2)
        atomicAdd(&aggT[q * 8 + j2][node_loc], acc[j2] + accB[j2]);
    __syncthreads();

    // epilogue: 8 threads/node, 4 outcols each
    int nl2 = tid >> 3;               // 0..31
    int cgrp = tid & 7;               // cols cgrp*4..+3
    int onode = (int)blockIdx.x * 32 + nl2;
    float dd = (onode < N) ? dinv[onode] : 0.f;
    float o0 = 0.f, o1 = 0.f, o2 = 0.f, o3 = 0.f;
    #pragma unroll
    for (int k = 0; k < 32; ++k) {
        float yk = fmaxf(aggT[k][nl2] * dd + b1[k], 0.f);
        float4 wv = *reinterpret_cast<const float4*>(&W2sh[k * 32 + cgrp * 4]);
        o0 += yk * wv.x; o1 += yk * wv.y; o2 += yk * wv.z; o3 += yk * wv.w;
    }
    if (onode <= N) {   // node N: dd=0 -> stores zeros (pad row for layer-2 gathers)
        __half2 pa = __floats2half2_rn(o0 * dd, o1 * dd);
        __half2 pb = __floats2half2_rn(o2 * dd, o3 * dd);
        uint2 st;
        st.x = *reinterpret_cast<unsigned int*>(&pa);
        st.y = *reinterpret_cast<unsigned int*>(&pb);
        *reinterpret_cast<uint2*>(hp2 + (size_t)onode * 32 + cgrp * 4) = st;
    }
}

// agg layer2 + bias + relu + head (64 outcols). Same structure as k_aggmm1.
__global__ __launch_bounds__(256)
void k_aggout(const __half* __restrict__ hp, const int* __restrict__ rowbeg,
              const int* __restrict__ rowend, const unsigned short* __restrict__ csr,
              const float* __restrict__ dinv, const float* __restrict__ b2,
              const float* __restrict__ Wo, const float* __restrict__ bo,
              float* __restrict__ out, int N) {
    __shared__ float aggT[32][33];
    __shared__ float Wosh[32 * 64];   // 8 KB
    int tid = threadIdx.x;
    int lane = tid & 63;
    int w = tid >> 6;
    int g = lane >> 2, q = lane & 3;
    int h = w & 1;
    int node_loc = (w >> 1) * 16 + g;
    int node = (int)blockIdx.x * 32 + node_loc;

    for (int i = tid; i < 1056; i += 256) (&aggT[0][0])[i] = 0.f;
    for (int i = tid; i < 512; i += 256)
        reinterpret_cast<float4*>(Wosh)[i] = reinterpret_cast<const float4*>(Wo)[i];
    __syncthreads();

    float acc[8], accB[8];
    #pragma unroll
    for (int t = 0; t < 8; ++t) { acc[t] = 0.f; accB[t] = 0.f; }
    int beg = 0, endx = 0;
    if (node < N) { beg = rowbeg[node]; endx = rowend[node]; }
    const uint4* hp4 = reinterpret_cast<const uint4*>(hp);
    for (int t = beg + 4 * h; t < endx; t += 8) {
        ushort4 s4 = *reinterpret_cast<const ushort4*>(csr + t);
        unsigned int i0 = (unsigned int)s4.x * 4u + q;
        unsigned int i1 = (unsigned int)s4.y * 4u + q;
        unsigned int i2 = (unsigned int)s4.z * 4u + q;
        unsigned int i3 = (unsigned int)s4.w * 4u + q;
        uint4 v0 = hp4[i0];
        uint4 v1 = hp4[i1];
        uint4 v2 = hp4[i2];
        uint4 v3 = hp4[i3];
        ACC8M(acc, v0); ACC8M(accB, v1); ACC8M(acc, v2); ACC8M(accB, v3);
    }
    #pragma unroll
    for (int j2 = 0; j2 < 8; ++j2)
        atomicAdd(&aggT[q * 8 + j2][node_loc], acc[j2] + accB[j2]);
    __syncthreads();

    // epilogue: 8 threads/node, 8 outcols each
    int nl2 = tid >> 3;
    int cgrp = tid & 7;               // cols cgrp*8..+7
    int onode = (int)blockIdx.x * 32 + nl2;
    float dd = (onode < N) ? dinv[onode] : 0.f;
    float o[8];
    #pragma unroll
    for (int i = 0; i < 8; ++i) o[i] = 0.f;
    #pragma unroll
    for (int k = 0; k < 32; ++k) {
        float yk = fmaxf(aggT[k][nl2] * dd + b2[k], 0.f);
        float4 wa = *reinterpret_cast<const float4*>(&Wosh[k * 64 + cgrp * 8]);
        float4 wb = *reinterpret_cast<const float4*>(&Wosh[k * 64 + cgrp * 8 + 4]);
        o[0] += yk * wa.x; o[1] += yk * wa.y; o[2] += yk * wa.z; o[3] += yk * wa.w;
        o[4] += yk * wb.x; o[5] += yk * wb.y; o[6] += yk * wb.z; o[7] += yk * wb.w;
    }
    if (onode < N) {
        float4 ba = *reinterpret_cast<const float4*>(bo + cgrp * 8);
        float4 bb = *reinterpret_cast<const float4*>(bo + cgrp * 8 + 4);
        float4 s0 = make_float4(o[0] + ba.x, o[1] + ba.y, o[2] + ba.z, o[3] + ba.w);
        float4 s1 = make_float4(o[4] + bb.x, o[5] + bb.y, o[6] + bb.z, o[7] + bb.w);
        float4* op = reinterpret_cast<float4*>(out + (size_t)onode * 64 + cgrp * 8);
        op[0] = s0;
        op[1] = s1;
    }
}

extern "C" void kernel_launch(void* const* d_in, const int* in_sizes, int n_in,
                              void* d_out, int out_size, void* d_ws, size_t ws_size,
                              hipStream_t stream) {
    const float* x  = (const float*)d_in[0];
    const int*   ei = (const int*)d_in[1];
    const float* W1 = (const float*)d_in[2];
    const float* b1 = (const float*)d_in[3];
    const float* W2 = (const float*)d_in[4];
    const float* b2 = (const float*)d_in[5];
    const float* Wo = (const float*)d_in[6];
    const float* bo = (const float*)d_in[7];
    float* out = (float*)d_out;

    const int N = in_sizes[0] / 128;   // 50000
    const int E = in_sizes[1] / 2;     // 1600000
    const int* src = ei;
    const int* dst = ei + E;

    char* ws = (char*)d_ws;
    size_t off = 0;
    auto alloc = [&](size_t bytes) {
        void* p = ws + off;
        off += (bytes + 255) & ~(size_t)255;
        return p;
    };
    int*            cursor = (int*)           alloc(512 * 4);
    unsigned int*   binned = (unsigned int*)  alloc((size_t)NBUCK * BCAP * 4);
    int*            rowbeg = (int*)           alloc((size_t)N * 4);
    int*            rowend = (int*)           alloc((size_t)N * 4);
    float*          dinv   = (float*)         alloc((size_t)N * 4);
    unsigned short* csr    = (unsigned short*)alloc((size_t)NBUCK * CCAP * 2);
    __half*         bufAh  = (__half*)        alloc((size_t)(N + 1) * 32 * 2);
    __half*         bufBh  = (__half*)        alloc((size_t)(N + 1) * 32 * 2);

    const int nbinA  = (E + CHUNK - 1) / CHUNK;      // 391
    const int nFront = NGEMM + nbinA;                // 587
    const int gAgg1  = (N + 1 + 31) / 32;            // covers pad node N
    const int gAgg2  = (N + 31) / 32;

    hipMemsetAsync(cursor, 0, 512 * 4, stream);
    k_front<<<nFront, 512, 0, stream>>>(x, W1, bufAh, N, src, dst, E,
                                        cursor, binned);
    k_binB<<<NBUCK, 512, 0, stream>>>(binned, cursor, rowbeg, rowend, dinv,
                                      csr, bufAh, N);
    k_aggmm1<<<gAgg1, 256, 0, stream>>>(bufAh, rowbeg, rowend, csr, dinv, b1,
                                        W2, bufBh, N);
    k_aggout<<<gAgg2, 256, 0, stream>>>(bufBh, rowbeg, rowend, csr, dinv, b2,
                                        Wo, bo, out, N);
}

// Round 5
// 198.185 us; speedup vs baseline: 1.1353x; 1.0147x over previous
//
#include <hip/hip_runtime.h>
#include <hip/hip_fp16.h>

#define CHUNK 4096        // edges per binA block
#define NBUCK 391         // buckets of 128 nodes (dst>>7)
#define BCAP  8192        // per-bucket edge capacity (mean 4096, 64 sigma slack)
#define CCAP  (BCAP+2048) // csr region capacity (edges + self + per-row pad to x16)
#define NGEMM 98          // gemm tiles of 512 rows (covers N+1 = 50001)

// Fused front kernel: gemm1 (x@W1 -> fp16) and binA (edge bucketing) are
// data-independent; one dispatch with interleaved block types overlaps them.
// Gemm path: 1 row/thread, x streamed from global (64B/step per lane), W1-only
// LDS (16KB broadcast reads) -> union LDS 22.6KB, no occupancy cap.
// binA path: wave-shfl scan (2 barriers instead of 18).
union FrontSmem {
    struct { float Wsh[128 * 32]; } g;                       // 16 KB
    struct { int cnt[512]; int lbase[512]; int gbs[512]; int wsum[8];
             unsigned int stage[CHUNK]; } a;                 // 22.6 KB
};

__global__ __launch_bounds__(512)
void k_front(const float* __restrict__ x, const float* __restrict__ W,
             __half* __restrict__ h, int N,
             const int* __restrict__ src, const int* __restrict__ dst, int E,
             int* __restrict__ cursor, unsigned int* __restrict__ binned) {
    __shared__ FrontSmem sm;
    int bid = (int)blockIdx.x;
    int tid = threadIdx.x;
    bool isg = (bid % 5 == 0) && (bid / 5 < NGEMM);

    if (isg) {
        // ---- gemm path: 512 rows/block, thread = 1 row x 32 cols
        float* Wsh = sm.g.Wsh;
        for (int j = tid; j < 1024; j += 512)
            reinterpret_cast<float4*>(Wsh)[j] = reinterpret_cast<const float4*>(W)[j];
        __syncthreads();
        int row = (bid / 5) * 512 + tid;
        const float4 z4 = make_float4(0.f, 0.f, 0.f, 0.f);
        float4 acc4[8];
        #pragma unroll
        for (int c = 0; c < 8; ++c) acc4[c] = z4;
        if (row < N) {
            const float4* xr = reinterpret_cast<const float4*>(x + (size_t)row * 128);
            float4 xv = xr[0];
            for (int k4 = 0; k4 < 32; ++k4) {
                float4 xn = (k4 < 31) ? xr[k4 + 1] : z4;   // prefetch next 16B
                const float* xp = reinterpret_cast<const float*>(&xv);
                #pragma unroll
                for (int j = 0; j < 4; ++j) {
                    float xj = xp[j];
                    const float4* wr = reinterpret_cast<const float4*>(Wsh + (k4 * 4 + j) * 32);
                    #pragma unroll
                    for (int c = 0; c < 8; ++c) {
                        float4 wv = wr[c];   // wave-uniform LDS address -> broadcast
                        acc4[c].x += xj * wv.x; acc4[c].y += xj * wv.y;
                        acc4[c].z += xj * wv.z; acc4[c].w += xj * wv.w;
                    }
                }
                xv = xn;
            }
        }
        if (row <= N) {   // row N (pad): acc stays zero -> zero row
            uint4 st[2];
            #pragma unroll
            for (int t = 0; t < 2; ++t) {
                __half2 h0 = __floats2half2_rn(acc4[t*4+0].x, acc4[t*4+0].y);
                __half2 h1 = __floats2half2_rn(acc4[t*4+0].z, acc4[t*4+0].w);
                __half2 h2 = __floats2half2_rn(acc4[t*4+1].x, acc4[t*4+1].y);
                __half2 h3 = __floats2half2_rn(acc4[t*4+1].z, acc4[t*4+1].w);
                st[0].x = *reinterpret_cast<unsigned int*>(&h0);
                st[0].y = *reinterpret_cast<unsigned int*>(&h1);
                st[0].z = *reinterpret_cast<unsigned int*>(&h2);
                st[0].w = *reinterpret_cast<unsigned int*>(&h3);
                __half2 h4 = __floats2half2_rn(acc4[t*4+2].x, acc4[t*4+2].y);
                __half2 h5 = __floats2half2_rn(acc4[t*4+2].z, acc4[t*4+2].w);
                __half2 h6 = __floats2half2_rn(acc4[t*4+3].x, acc4[t*4+3].y);
                __half2 h7 = __floats2half2_rn(acc4[t*4+3].z, acc4[t*4+3].w);
                st[1].x = *reinterpret_cast<unsigned int*>(&h4);
                st[1].y = *reinterpret_cast<unsigned int*>(&h5);
                st[1].z = *reinterpret_cast<unsigned int*>(&h6);
                st[1].w = *reinterpret_cast<unsigned int*>(&h7);
                uint4* op = reinterpret_cast<uint4*>(h + (size_t)row * 32 + t * 16);
                op[0] = st[0];
                op[1] = st[1];
            }
        }
        return;
    }

    // ---- binA path: rank -> wave-shfl scan -> LDS stage -> run writes
    int gcount = bid / 5 + 1; if (gcount > NGEMM) gcount = NGEMM;
    int abid = bid - gcount;
    int* cnt = sm.a.cnt;
    int* lbase = sm.a.lbase;
    int* gbs = sm.a.gbs;
    unsigned int* stage = sm.a.stage;
    cnt[tid] = 0;
    __syncthreads();
    int base = abid * CHUNK;
    unsigned int pk[8];
    int rk[8];
    unsigned int mask = 0;
    #pragma unroll
    for (int i = 0; i < 2; ++i) {
        int e = base + i * 2048 + tid * 4;
        if (e + 3 < E) {
            int4 d4 = *reinterpret_cast<const int4*>(dst + e);
            int4 s4 = *reinterpret_cast<const int4*>(src + e);
            pk[i*4+0] = ((unsigned)d4.x << 16) | (unsigned)s4.x; rk[i*4+0] = atomicAdd(&cnt[d4.x >> 7], 1);
            pk[i*4+1] = ((unsigned)d4.y << 16) | (unsigned)s4.y; rk[i*4+1] = atomicAdd(&cnt[d4.y >> 7], 1);
            pk[i*4+2] = ((unsigned)d4.z << 16) | (unsigned)s4.z; rk[i*4+2] = atomicAdd(&cnt[d4.z >> 7], 1);
            pk[i*4+3] = ((unsigned)d4.w << 16) | (unsigned)s4.w; rk[i*4+3] = atomicAdd(&cnt[d4.w >> 7], 1);
            mask |= 0xFu << (i * 4);
        } else {
            for (int j = 0; j < 4; ++j) {
                int k = e + j;
                if (k < E) {
                    int d = dst[k], s = src[k];
                    pk[i*4+j] = ((unsigned)d << 16) | (unsigned)s;
                    rk[i*4+j] = atomicAdd(&cnt[d >> 7], 1);
                    mask |= 1u << (i * 4 + j);
                }
            }
        }
    }
    __syncthreads();
    int myc = cnt[tid];
    int lid = tid & 63, wid = tid >> 6;
    int v = myc;
    #pragma unroll
    for (int d = 1; d < 64; d <<= 1) {
        int u = __shfl_up(v, d, 64);
        if (lid >= d) v += u;
    }
    if (lid == 63) sm.a.wsum[wid] = v;
    __syncthreads();
    int pre = 0, tot = 0;
    #pragma unroll
    for (int w2 = 0; w2 < 8; ++w2) {
        int s = sm.a.wsum[w2];
        tot += s;
        if (w2 < wid) pre += s;
    }
    int inc = v + pre;                 // global inclusive prefix
    lbase[tid] = inc - myc;
    gbs[tid] = myc ? atomicAdd(&cursor[tid], myc) : 0;
    int nvalid = tot;
    __syncthreads();
    #pragma unroll
    for (int i = 0; i < 8; ++i) {
        if (mask & (1u << i)) {
            int b = pk[i] >> 23;
            stage[lbase[b] + rk[i]] = pk[i];
        }
    }
    __syncthreads();
    for (int i = tid; i < nvalid; i += 512) {
        unsigned int v2 = stage[i];
        int b = v2 >> 23;
        binned[(size_t)b * BCAP + gbs[b] + (i - lbase[b])] = v2;
    }
}

// binB: one block per 128-node bucket. Single pass with rank recording.
// rowend stores the EXACT end (self + edges, no pad): agg kernels skip pads.
__global__ __launch_bounds__(512)
void k_binB(const unsigned int* __restrict__ binned, const int* __restrict__ cursor,
            int* __restrict__ rowbeg, int* __restrict__ rowend, float* __restrict__ dinvg,
            unsigned short* __restrict__ csr, __half* __restrict__ hh, int N) {
    __shared__ int cnt[128];
    __shared__ int sc[128];
    __shared__ int excls[128];
    __shared__ float dv[128];
    int tid = threadIdx.x;
    int b = blockIdx.x;
    size_t ebase = (size_t)b * BCAP;
    int ne = cursor[b];
    if (tid < 128) cnt[tid] = 0;
    __syncthreads();
    unsigned int pk[16];
    int rk[16];
    #pragma unroll
    for (int ii = 0; ii < 16; ++ii) {
        int i = ii * 512 + tid;
        if (i < ne) {
            pk[ii] = binned[ebase + i];
            rk[ii] = atomicAdd(&cnt[(pk[ii] >> 16) & 127], 1);
        }
    }
    __syncthreads();
    int myc = 0, pcnt = 0;
    if (tid < 128) {
        myc = cnt[tid];
        pcnt = (myc + 1 + 15) & ~15;   // self + edges, padded to x16 (region layout)
        sc[tid] = pcnt;
    }
    __syncthreads();
    for (int off = 1; off < 128; off <<= 1) {
        int v = 0;
        if (tid < 128 && tid >= off) v = sc[tid - off];
        __syncthreads();
        if (tid < 128) sc[tid] += v;
        __syncthreads();
    }
    int cbase = b * CCAP;
    if (tid < 128) {
        int pexcl = sc[tid] - pcnt;
        excls[tid] = pexcl;
        int node = (b << 7) + tid;
        int rb = cbase + pexcl;
        float di = rsqrtf((float)(myc + 1));
        dv[tid] = di;
        if (node < N) {
            rowbeg[node] = rb;
            rowend[node] = rb + 1 + myc;   // EXACT end (pads excluded)
            dinvg[node] = di;
            csr[rb] = (unsigned short)node;   // self entry first
        }
    }
    __syncthreads();
    #pragma unroll
    for (int ii = 0; ii < 16; ++ii) {
        int i = ii * 512 + tid;
        if (i < ne) {
            int nl = (pk[ii] >> 16) & 127;
            csr[cbase + excls[nl] + 1 + rk[ii]] = (unsigned short)(pk[ii] & 0xFFFFu);
        }
    }
    __syncthreads();
    if (tid < 128) {   // fill pad slots with dummy node N (zero row) -- chunk overreads hit these
        int pexcl = excls[tid];
        for (int p = pexcl + 1 + myc; p < pexcl + pcnt; ++p)
            csr[cbase + p] = (unsigned short)N;
    }
    __syncthreads();
    // scale h rows of this bucket by dinv (fp16 in place): 128 rows x 4 uint4
    uint4* h4 = reinterpret_cast<uint4*>(hh);
    size_t hbase = (size_t)(b << 7) * 4;
    {
        int nl = tid >> 2;
        if (((b << 7) + nl) < N) {
            uint4 v = h4[hbase + tid];
            float d = dv[nl];
            __half2* hv = reinterpret_cast<__half2*>(&v);
            #pragma unroll
            for (int t = 0; t < 4; ++t) {
                float2 f = __half22float2(hv[t]);
                hv[t] = __floats2half2_rn(f.x * d, f.y * d);
            }
            h4[hbase + tid] = v;
        }
    }
}

// fp16 -> fp32 accumulate in ONE instruction per feature: v_fma_mix_f32
#define MIXLO(ACC, U) asm("v_fma_mix_f32 %0, %1, 1.0, %0 op_sel:[0,0,0] op_sel_hi:[1,0,0]" : "+v"(ACC) : "v"(U))
#define MIXHI(ACC, U) asm("v_fma_mix_f32 %0, %1, 1.0, %0 op_sel:[1,0,0] op_sel_hi:[1,0,0]" : "+v"(ACC) : "v"(U))
#define ACC8M(A, V) do {            \
    MIXLO((A)[0], (V).x); MIXHI((A)[1], (V).x); \
    MIXLO((A)[2], (V).y); MIXHI((A)[3], (V).y); \
    MIXLO((A)[4], (V).z); MIXHI((A)[5], (V).z); \
    MIXLO((A)[6], (V).w); MIXHI((A)[7], (V).w); \
} while (0)

// agg layer1 + bias + relu + gemm2 + dinv pre-scale.
// 32 nodes/block, 4 lanes per node: per-lane per-feature partials, no cross-lane
// reduce; partials combine via LDS atomics into aggT; block-level LDS matvec.
__global__ __launch_bounds__(256)
void k_aggmm1(const __half* __restrict__ hp, const int* __restrict__ rowbeg,
              const int* __restrict__ rowend, const unsigned short* __restrict__ csr,
              const float* __restrict__ dinv, const float* __restrict__ b1,
              const float* __restrict__ W2, __half* __restrict__ hp2, int N) {
    __shared__ float aggT[32][33];    // [feature][node], pitch 33
    __shared__ float W2sh[32 * 32];   // 4 KB
    int tid = threadIdx.x;
    int lane = tid & 63;
    int w = tid >> 6;
    int g = lane >> 2, q = lane & 3;
    int h = w & 1;                    // row-split half
    int node_loc = (w >> 1) * 16 + g; // 0..31
    int node = (int)blockIdx.x * 32 + node_loc;

    for (int i = tid; i < 1056; i += 256) (&aggT[0][0])[i] = 0.f;
    for (int i = tid; i < 256; i += 256)
        reinterpret_cast<float4*>(W2sh)[i] = reinterpret_cast<const float4*>(W2)[i];
    __syncthreads();

    float acc[8], accB[8];
    #pragma unroll
    for (int t = 0; t < 8; ++t) { acc[t] = 0.f; accB[t] = 0.f; }
    int beg = 0, endx = 0;
    if (node < N) { beg = rowbeg[node]; endx = rowend[node]; }
    const uint4* hp4 = reinterpret_cast<const uint4*>(hp);
    for (int t = beg + 4 * h; t < endx; t += 8) {
        ushort4 s4 = *reinterpret_cast<const ushort4*>(csr + t);  // overread -> pads (=N, zero row)
        unsigned int i0 = (unsigned int)s4.x * 4u + q;
        unsigned int i1 = (unsigned int)s4.y * 4u + q;
        unsigned int i2 = (unsigned int)s4.z * 4u + q;
        unsigned int i3 = (unsigned int)s4.w * 4u + q;
        uint4 v0 = hp4[i0];
        uint4 v1 = hp4[i1];
        uint4 v2 = hp4[i2];
        uint4 v3 = hp4[i3];
        ACC8M(acc, v0); ACC8M(accB, v1); ACC8M(acc, v2); ACC8M(accB, v3);
    }
    #pragma unroll
    for (int j2 = 0; j2 < 8; ++j2)
        atomicAdd(&aggT[q * 8 + j2][node_loc], acc[j2] + accB[j2]);
    __syncthreads();

    // epilogue: 8 threads/node, 4 outcols each
    int nl2 = tid >> 3;               // 0..31
    int cgrp = tid & 7;               // cols cgrp*4..+3
    int onode = (int)blockIdx.x * 32 + nl2;
    float dd = (onode < N) ? dinv[onode] : 0.f;
    float o0 = 0.f, o1 = 0.f, o2 = 0.f, o3 = 0.f;
    #pragma unroll
    for (int k = 0; k < 32; ++k) {
        float yk = fmaxf(aggT[k][nl2] * dd + b1[k], 0.f);
        float4 wv = *reinterpret_cast<const float4*>(&W2sh[k * 32 + cgrp * 4]);
        o0 += yk * wv.x; o1 += yk * wv.y; o2 += yk * wv.z; o3 += yk * wv.w;
    }
    if (onode <= N) {   // node N: dd=0 -> stores zeros (pad row for layer-2 gathers)
        __half2 pa = __floats2half2_rn(o0 * dd, o1 * dd);
        __half2 pb = __floats2half2_rn(o2 * dd, o3 * dd);
        uint2 st;
        st.x = *reinterpret_cast<unsigned int*>(&pa);
        st.y = *reinterpret_cast<unsigned int*>(&pb);
        *reinterpret_cast<uint2*>(hp2 + (size_t)onode * 32 + cgrp * 4) = st;
    }
}

// agg layer2 + bias + relu + head (64 outcols). Same structure as k_aggmm1.
__global__ __launch_bounds__(256)
void k_aggout(const __half* __restrict__ hp, const int* __restrict__ rowbeg,
              const int* __restrict__ rowend, const unsigned short* __restrict__ csr,
              const float* __restrict__ dinv, const float* __restrict__ b2,
              const float* __restrict__ Wo, const float* __restrict__ bo,
              float* __restrict__ out, int N) {
    __shared__ float aggT[32][33];
    __shared__ float Wosh[32 * 64];   // 8 KB
    int tid = threadIdx.x;
    int lane = tid & 63;
    int w = tid >> 6;
    int g = lane >> 2, q = lane & 3;
    int h = w & 1;
    int node_loc = (w >> 1) * 16 + g;
    int node = (int)blockIdx.x * 32 + node_loc;

    for (int i = tid; i < 1056; i += 256) (&aggT[0][0])[i] = 0.f;
    for (int i = tid; i < 512; i += 256)
        reinterpret_cast<float4*>(Wosh)[i] = reinterpret_cast<const float4*>(Wo)[i];
    __syncthreads();

    float acc[8], accB[8];
    #pragma unroll
    for (int t = 0; t < 8; ++t) { acc[t] = 0.f; accB[t] = 0.f; }
    int beg = 0, endx = 0;
    if (node < N) { beg = rowbeg[node]; endx = rowend[node]; }
    const uint4* hp4 = reinterpret_cast<const uint4*>(hp);
    for (int t = beg + 4 * h; t < endx; t += 8) {
        ushort4 s4 = *reinterpret_cast<const ushort4*>(csr + t);
        unsigned int i0 = (unsigned int)s4.x * 4u + q;
        unsigned int i1 = (unsigned int)s4.y * 4u + q;
        unsigned int i2 = (unsigned int)s4.z * 4u + q;
        unsigned int i3 = (unsigned int)s4.w * 4u + q;
        uint4 v0 = hp4[i0];
        uint4 v1 = hp4[i1];
        uint4 v2 = hp4[i2];
        uint4 v3 = hp4[i3];
        ACC8M(acc, v0); ACC8M(accB, v1); ACC8M(acc, v2); ACC8M(accB, v3);
    }
    #pragma unroll
    for (int j2 = 0; j2 < 8; ++j2)
        atomicAdd(&aggT[q * 8 + j2][node_loc], acc[j2] + accB[j2]);
    __syncthreads();

    // epilogue: 8 threads/node, 8 outcols each
    int nl2 = tid >> 3;
    int cgrp = tid & 7;               // cols cgrp*8..+7
    int onode = (int)blockIdx.x * 32 + nl2;
    float dd = (onode < N) ? dinv[onode] : 0.f;
    float o[8];
    #pragma unroll
    for (int i = 0; i < 8; ++i) o[i] = 0.f;
    #pragma unroll
    for (int k = 0; k < 32; ++k) {
        float yk = fmaxf(aggT[k][nl2] * dd + b2[k], 0.f);
        float4 wa = *reinterpret_cast<const float4*>(&Wosh[k * 64 + cgrp * 8]);
        float4 wb = *reinterpret_cast<const float4*>(&Wosh[k * 64 + cgrp * 8 + 4]);
        o[0] += yk * wa.x; o[1] += yk * wa.y; o[2] += yk * wa.z; o[3] += yk * wa.w;
        o[4] += yk * wb.x; o[5] += yk * wb.y; o[6] += yk * wb.z; o[7] += yk * wb.w;
    }
    if (onode < N) {
        float4 ba = *reinterpret_cast<const float4*>(bo + cgrp * 8);
        float4 bb = *reinterpret_cast<const float4*>(bo + cgrp * 8 + 4);
        float4 s0 = make_float4(o[0] + ba.x, o[1] + ba.y, o[2] + ba.z, o[3] + ba.w);
        float4 s1 = make_float4(o[4] + bb.x, o[5] + bb.y, o[6] + bb.z, o[7] + bb.w);
        float4* op = reinterpret_cast<float4*>(out + (size_t)onode * 64 + cgrp * 8);
        op[0] = s0;
        op[1] = s1;
    }
}

extern "C" void kernel_launch(void* const* d_in, const int* in_sizes, int n_in,
                              void* d_out, int out_size, void* d_ws, size_t ws_size,
                              hipStream_t stream) {
    const float* x  = (const float*)d_in[0];
    const int*   ei = (const int*)d_in[1];
    const float* W1 = (const float*)d_in[2];
    const float* b1 = (const float*)d_in[3];
    const float* W2 = (const float*)d_in[4];
    const float* b2 = (const float*)d_in[5];
    const float* Wo = (const float*)d_in[6];
    const float* bo = (const float*)d_in[7];
    float* out = (float*)d_out;

    const int N = in_sizes[0] / 128;   // 50000
    const int E = in_sizes[1] / 2;     // 1600000
    const int* src = ei;
    const int* dst = ei + E;

    char* ws = (char*)d_ws;
    size_t off = 0;
    auto alloc = [&](size_t bytes) {
        void* p = ws + off;
        off += (bytes + 255) & ~(size_t)255;
        return p;
    };
    int*            cursor = (int*)           alloc(512 * 4);
    unsigned int*   binned = (unsigned int*)  alloc((size_t)NBUCK * BCAP * 4);
    int*            rowbeg = (int*)           alloc((size_t)N * 4);
    int*            rowend = (int*)           alloc((size_t)N * 4);
    float*          dinv   = (float*)         alloc((size_t)N * 4);
    unsigned short* csr    = (unsigned short*)alloc((size_t)NBUCK * CCAP * 2);
    __half*         bufAh  = (__half*)        alloc((size_t)(N + 1) * 32 * 2);
    __half*         bufBh  = (__half*)        alloc((size_t)(N + 1) * 32 * 2);

    const int nbinA  = (E + CHUNK - 1) / CHUNK;      // 391
    const int nFront = NGEMM + nbinA;                // 489
    const int gAgg1  = (N + 1 + 31) / 32;            // covers pad node N
    const int gAgg2  = (N + 31) / 32;

    hipMemsetAsync(cursor, 0, 512 * 4, stream);
    k_front<<<nFront, 512, 0, stream>>>(x, W1, bufAh, N, src, dst, E,
                                        cursor, binned);
    k_binB<<<NBUCK, 512, 0, stream>>>(binned, cursor, rowbeg, rowend, dinv,
                                      csr, bufAh, N);
    k_aggmm1<<<gAgg1, 256, 0, stream>>>(bufAh, rowbeg, rowend, csr, dinv, b1,
                                        W2, bufBh, N);
    k_aggout<<<gAgg2, 256, 0, stream>>>(bufBh, rowbeg, rowend, csr, dinv, b2,
                                        Wo, bo, out, N);
}

// Round 6
// 190.972 us; speedup vs baseline: 1.1782x; 1.0378x over previous
//
#include <hip/hip_runtime.h>
#include <hip/hip_fp16.h>

#define CHUNK 4096        // edges per binA block
#define NBUCK 391         // buckets of 128 nodes (dst>>7)
#define BCAP  8192        // per-bucket edge capacity (mean 4096, 64 sigma slack)
#define CCAP  (BCAP+2048) // csr region capacity (edges + self + per-row pad to x16)
#define NGEMM 98          // gemm tiles of 512 rows (covers N+1 = 50001)

// Fused front kernel: gemm1 (x@W1 -> fp16) and binA (edge bucketing) are
// data-independent; one dispatch with interleaved block types overlaps them.
// Gemm path: 1 row/thread, x streamed via ping-pong 64B register buffers
// (4 float4 in flight vs cold-HBM ~900cy latency), W1-only LDS broadcast.
// binA path: wave-shfl scan (2 barriers).
union FrontSmem {
    struct { float Wsh[128 * 32]; } g;                       // 16 KB
    struct { int cnt[512]; int lbase[512]; int gbs[512]; int wsum[8];
             unsigned int stage[CHUNK]; } a;                 // 22.6 KB
};

__global__ __launch_bounds__(512)
void k_front(const float* __restrict__ x, const float* __restrict__ W,
             __half* __restrict__ h, int N,
             const int* __restrict__ src, const int* __restrict__ dst, int E,
             int* __restrict__ cursor, unsigned int* __restrict__ binned) {
    __shared__ FrontSmem sm;
    int bid = (int)blockIdx.x;
    int tid = threadIdx.x;
    bool isg = (bid % 5 == 0) && (bid / 5 < NGEMM);

    if (isg) {
        // ---- gemm path: 512 rows/block, thread = 1 row x 32 cols
        float* Wsh = sm.g.Wsh;
        for (int j = tid; j < 1024; j += 512)
            reinterpret_cast<float4*>(Wsh)[j] = reinterpret_cast<const float4*>(W)[j];
        __syncthreads();
        int row = (bid / 5) * 512 + tid;
        const float4 z4 = make_float4(0.f, 0.f, 0.f, 0.f);
        float4 acc4[8];
        #pragma unroll
        for (int c = 0; c < 8; ++c) acc4[c] = z4;
        if (row < N) {
            const float4* xr = reinterpret_cast<const float4*>(x + (size_t)row * 128);
            float4 bufA[4], bufB[4];
            #pragma unroll
            for (int i = 0; i < 4; ++i) bufA[i] = xr[i];
            #pragma unroll
            for (int blk = 0; blk < 8; ++blk) {
                // prefetch next 64B chunk into the other buffer (static ping-pong)
                if (blk < 7) {
                    if ((blk & 1) == 0) {
                        #pragma unroll
                        for (int i = 0; i < 4; ++i) bufB[i] = xr[(blk + 1) * 4 + i];
                    } else {
                        #pragma unroll
                        for (int i = 0; i < 4; ++i) bufA[i] = xr[(blk + 1) * 4 + i];
                    }
                }
                #pragma unroll
                for (int i = 0; i < 4; ++i) {
                    float4 xv = ((blk & 1) == 0) ? bufA[i] : bufB[i];
                    const float* xp = reinterpret_cast<const float*>(&xv);
                    #pragma unroll
                    for (int j = 0; j < 4; ++j) {
                        float xj = xp[j];
                        const float4* wr = reinterpret_cast<const float4*>(
                            Wsh + ((blk * 4 + i) * 4 + j) * 32);
                        #pragma unroll
                        for (int c = 0; c < 8; ++c) {
                            float4 wv = wr[c];   // wave-uniform LDS -> broadcast
                            acc4[c].x += xj * wv.x; acc4[c].y += xj * wv.y;
                            acc4[c].z += xj * wv.z; acc4[c].w += xj * wv.w;
                        }
                    }
                }
            }
        }
        if (row <= N) {   // row N (pad): acc stays zero -> zero row
            uint4 st[2];
            #pragma unroll
            for (int t = 0; t < 2; ++t) {
                __half2 h0 = __floats2half2_rn(acc4[t*4+0].x, acc4[t*4+0].y);
                __half2 h1 = __floats2half2_rn(acc4[t*4+0].z, acc4[t*4+0].w);
                __half2 h2 = __floats2half2_rn(acc4[t*4+1].x, acc4[t*4+1].y);
                __half2 h3 = __floats2half2_rn(acc4[t*4+1].z, acc4[t*4+1].w);
                st[0].x = *reinterpret_cast<unsigned int*>(&h0);
                st[0].y = *reinterpret_cast<unsigned int*>(&h1);
                st[0].z = *reinterpret_cast<unsigned int*>(&h2);
                st[0].w = *reinterpret_cast<unsigned int*>(&h3);
                __half2 h4 = __floats2half2_rn(acc4[t*4+2].x, acc4[t*4+2].y);
                __half2 h5 = __floats2half2_rn(acc4[t*4+2].z, acc4[t*4+2].w);
                __half2 h6 = __floats2half2_rn(acc4[t*4+3].x, acc4[t*4+3].y);
                __half2 h7 = __floats2half2_rn(acc4[t*4+3].z, acc4[t*4+3].w);
                st[1].x = *reinterpret_cast<unsigned int*>(&h4);
                st[1].y = *reinterpret_cast<unsigned int*>(&h5);
                st[1].z = *reinterpret_cast<unsigned int*>(&h6);
                st[1].w = *reinterpret_cast<unsigned int*>(&h7);
                uint4* op = reinterpret_cast<uint4*>(h + (size_t)row * 32 + t * 16);
                op[0] = st[0];
                op[1] = st[1];
            }
        }
        return;
    }

    // ---- binA path: rank -> wave-shfl scan -> LDS stage -> run writes
    int gcount = bid / 5 + 1; if (gcount > NGEMM) gcount = NGEMM;
    int abid = bid - gcount;
    int* cnt = sm.a.cnt;
    int* lbase = sm.a.lbase;
    int* gbs = sm.a.gbs;
    unsigned int* stage = sm.a.stage;
    cnt[tid] = 0;
    __syncthreads();
    int base = abid * CHUNK;
    unsigned int pk[8];
    int rk[8];
    unsigned int mask = 0;
    #pragma unroll
    for (int i = 0; i < 2; ++i) {
        int e = base + i * 2048 + tid * 4;
        if (e + 3 < E) {
            int4 d4 = *reinterpret_cast<const int4*>(dst + e);
            int4 s4 = *reinterpret_cast<const int4*>(src + e);
            pk[i*4+0] = ((unsigned)d4.x << 16) | (unsigned)s4.x; rk[i*4+0] = atomicAdd(&cnt[d4.x >> 7], 1);
            pk[i*4+1] = ((unsigned)d4.y << 16) | (unsigned)s4.y; rk[i*4+1] = atomicAdd(&cnt[d4.y >> 7], 1);
            pk[i*4+2] = ((unsigned)d4.z << 16) | (unsigned)s4.z; rk[i*4+2] = atomicAdd(&cnt[d4.z >> 7], 1);
            pk[i*4+3] = ((unsigned)d4.w << 16) | (unsigned)s4.w; rk[i*4+3] = atomicAdd(&cnt[d4.w >> 7], 1);
            mask |= 0xFu << (i * 4);
        } else {
            for (int j = 0; j < 4; ++j) {
                int k = e + j;
                if (k < E) {
                    int d = dst[k], s = src[k];
                    pk[i*4+j] = ((unsigned)d << 16) | (unsigned)s;
                    rk[i*4+j] = atomicAdd(&cnt[d >> 7], 1);
                    mask |= 1u << (i * 4 + j);
                }
            }
        }
    }
    __syncthreads();
    int myc = cnt[tid];
    int lid = tid & 63, wid = tid >> 6;
    int v = myc;
    #pragma unroll
    for (int d = 1; d < 64; d <<= 1) {
        int u = __shfl_up(v, d, 64);
        if (lid >= d) v += u;
    }
    if (lid == 63) sm.a.wsum[wid] = v;
    __syncthreads();
    int pre = 0, tot = 0;
    #pragma unroll
    for (int w2 = 0; w2 < 8; ++w2) {
        int s = sm.a.wsum[w2];
        tot += s;
        if (w2 < wid) pre += s;
    }
    int inc = v + pre;                 // global inclusive prefix
    lbase[tid] = inc - myc;
    gbs[tid] = myc ? atomicAdd(&cursor[tid], myc) : 0;
    int nvalid = tot;
    __syncthreads();
    #pragma unroll
    for (int i = 0; i < 8; ++i) {
        if (mask & (1u << i)) {
            int b = pk[i] >> 23;
            stage[lbase[b] + rk[i]] = pk[i];
        }
    }
    __syncthreads();
    for (int i = tid; i < nvalid; i += 512) {
        unsigned int v2 = stage[i];
        int b = v2 >> 23;
        binned[(size_t)b * BCAP + gbs[b] + (i - lbase[b])] = v2;
    }
}

// binB: one block per 128-node bucket. Single pass with rank recording.
// rowend stores the EXACT end (self + edges, no pad): agg kernels skip pads.
__global__ __launch_bounds__(512)
void k_binB(const unsigned int* __restrict__ binned, const int* __restrict__ cursor,
            int* __restrict__ rowbeg, int* __restrict__ rowend, float* __restrict__ dinvg,
            unsigned short* __restrict__ csr, __half* __restrict__ hh, int N) {
    __shared__ int cnt[128];
    __shared__ int sc[128];
    __shared__ int excls[128];
    __shared__ float dv[128];
    int tid = threadIdx.x;
    int b = blockIdx.x;
    size_t ebase = (size_t)b * BCAP;
    int ne = cursor[b];
    if (tid < 128) cnt[tid] = 0;
    __syncthreads();
    unsigned int pk[16];
    int rk[16];
    #pragma unroll
    for (int ii = 0; ii < 16; ++ii) {
        int i = ii * 512 + tid;
        if (i < ne) {
            pk[ii] = binned[ebase + i];
            rk[ii] = atomicAdd(&cnt[(pk[ii] >> 16) & 127], 1);
        }
    }
    __syncthreads();
    int myc = 0, pcnt = 0;
    if (tid < 128) {
        myc = cnt[tid];
        pcnt = (myc + 1 + 15) & ~15;   // self + edges, padded to x16 (region layout)
        sc[tid] = pcnt;
    }
    __syncthreads();
    for (int off = 1; off < 128; off <<= 1) {
        int v = 0;
        if (tid < 128 && tid >= off) v = sc[tid - off];
        __syncthreads();
        if (tid < 128) sc[tid] += v;
        __syncthreads();
    }
    int cbase = b * CCAP;
    if (tid < 128) {
        int pexcl = sc[tid] - pcnt;
        excls[tid] = pexcl;
        int node = (b << 7) + tid;
        int rb = cbase + pexcl;
        float di = rsqrtf((float)(myc + 1));
        dv[tid] = di;
        if (node < N) {
            rowbeg[node] = rb;
            rowend[node] = rb + 1 + myc;   // EXACT end (pads excluded)
            dinvg[node] = di;
            csr[rb] = (unsigned short)node;   // self entry first
        }
    }
    __syncthreads();
    #pragma unroll
    for (int ii = 0; ii < 16; ++ii) {
        int i = ii * 512 + tid;
        if (i < ne) {
            int nl = (pk[ii] >> 16) & 127;
            csr[cbase + excls[nl] + 1 + rk[ii]] = (unsigned short)(pk[ii] & 0xFFFFu);
        }
    }
    __syncthreads();
    if (tid < 128) {   // fill pad slots with dummy node N (zero row) -- chunk overreads hit these
        int pexcl = excls[tid];
        for (int p = pexcl + 1 + myc; p < pexcl + pcnt; ++p)
            csr[cbase + p] = (unsigned short)N;
    }
    __syncthreads();
    // scale h rows of this bucket by dinv (fp16 in place): 128 rows x 4 uint4
    uint4* h4 = reinterpret_cast<uint4*>(hh);
    size_t hbase = (size_t)(b << 7) * 4;
    {
        int nl = tid >> 2;
        if (((b << 7) + nl) < N) {
            uint4 v = h4[hbase + tid];
            float d = dv[nl];
            __half2* hv = reinterpret_cast<__half2*>(&v);
            #pragma unroll
            for (int t = 0; t < 4; ++t) {
                float2 f = __half22float2(hv[t]);
                hv[t] = __floats2half2_rn(f.x * d, f.y * d);
            }
            h4[hbase + tid] = v;
        }
    }
}

// fp16 -> fp32 accumulate in ONE instruction per feature: v_fma_mix_f32
#define MIXLO(ACC, U) asm("v_fma_mix_f32 %0, %1, 1.0, %0 op_sel:[0,0,0] op_sel_hi:[1,0,0]" : "+v"(ACC) : "v"(U))
#define MIXHI(ACC, U) asm("v_fma_mix_f32 %0, %1, 1.0, %0 op_sel:[1,0,0] op_sel_hi:[1,0,0]" : "+v"(ACC) : "v"(U))
#define ACC8M(A, V) do {            \
    MIXLO((A)[0], (V).x); MIXHI((A)[1], (V).x); \
    MIXLO((A)[2], (V).y); MIXHI((A)[3], (V).y); \
    MIXLO((A)[4], (V).z); MIXHI((A)[5], (V).z); \
    MIXLO((A)[6], (V).w); MIXHI((A)[7], (V).w); \
} while (0)

// agg layer1 + bias + relu + gemm2 + dinv pre-scale.
// 32 nodes/block, 4 lanes per node; 8 entries per iteration (one uint4 csr read
// + 8 independent uint4 gathers in flight) -> half the full-latency stalls vs 4.
__global__ __launch_bounds__(256)
void k_aggmm1(const __half* __restrict__ hp, const int* __restrict__ rowbeg,
              const int* __restrict__ rowend, const unsigned short* __restrict__ csr,
              const float* __restrict__ dinv, const float* __restrict__ b1,
              const float* __restrict__ W2, __half* __restrict__ hp2, int N) {
    __shared__ float aggT[32][33];    // [feature][node], pitch 33
    __shared__ float W2sh[32 * 32];   // 4 KB
    int tid = threadIdx.x;
    int lane = tid & 63;
    int w = tid >> 6;
    int g = lane >> 2, q = lane & 3;
    int h = w & 1;                    // row-split half (8-entry blocks interleaved)
    int node_loc = (w >> 1) * 16 + g; // 0..31
    int node = (int)blockIdx.x * 32 + node_loc;

    for (int i = tid; i < 1056; i += 256) (&aggT[0][0])[i] = 0.f;
    for (int i = tid; i < 256; i += 256)
        reinterpret_cast<float4*>(W2sh)[i] = reinterpret_cast<const float4*>(W2)[i];
    __syncthreads();

    float acc[8], accB[8];
    #pragma unroll
    for (int t = 0; t < 8; ++t) { acc[t] = 0.f; accB[t] = 0.f; }
    int beg = 0, endx = 0;
    if (node < N) { beg = rowbeg[node]; endx = rowend[node]; }
    const uint4* hp4 = reinterpret_cast<const uint4*>(hp);
    for (int t = beg + 8 * h; t < endx; t += 16) {
        uint4 c4 = *reinterpret_cast<const uint4*>(csr + t);  // 8 ushorts; overread -> pads (=N)
        unsigned a0 = c4.x & 0xFFFFu, a1 = c4.x >> 16;
        unsigned a2 = c4.y & 0xFFFFu, a3 = c4.y >> 16;
        unsigned a4 = c4.z & 0xFFFFu, a5 = c4.z >> 16;
        unsigned a6 = c4.w & 0xFFFFu, a7 = c4.w >> 16;
        uint4 v0 = hp4[(size_t)a0 * 4 + q];
        uint4 v1 = hp4[(size_t)a1 * 4 + q];
        uint4 v2 = hp4[(size_t)a2 * 4 + q];
        uint4 v3 = hp4[(size_t)a3 * 4 + q];
        uint4 v4 = hp4[(size_t)a4 * 4 + q];
        uint4 v5 = hp4[(size_t)a5 * 4 + q];
        uint4 v6 = hp4[(size_t)a6 * 4 + q];
        uint4 v7 = hp4[(size_t)a7 * 4 + q];
        ACC8M(acc, v0); ACC8M(accB, v1); ACC8M(acc, v2); ACC8M(accB, v3);
        ACC8M(acc, v4); ACC8M(accB, v5); ACC8M(acc, v6); ACC8M(accB, v7);
    }
    #pragma unroll
    for (int j2 = 0; j2 < 8; ++j2)
        atomicAdd(&aggT[q * 8 + j2][node_loc], acc[j2] + accB[j2]);
    __syncthreads();

    // epilogue: 8 threads/node, 4 outcols each
    int nl2 = tid >> 3;               // 0..31
    int cgrp = tid & 7;               // cols cgrp*4..+3
    int onode = (int)blockIdx.x * 32 + nl2;
    float dd = (onode < N) ? dinv[onode] : 0.f;
    float o0 = 0.f, o1 = 0.f, o2 = 0.f, o3 = 0.f;
    #pragma unroll
    for (int k = 0; k < 32; ++k) {
        float yk = fmaxf(aggT[k][nl2] * dd + b1[k], 0.f);
        float4 wv = *reinterpret_cast<const float4*>(&W2sh[k * 32 + cgrp * 4]);
        o0 += yk * wv.x; o1 += yk * wv.y; o2 += yk * wv.z; o3 += yk * wv.w;
    }
    if (onode <= N) {   // node N: dd=0 -> stores zeros (pad row for layer-2 gathers)
        __half2 pa = __floats2half2_rn(o0 * dd, o1 * dd);
        __half2 pb = __floats2half2_rn(o2 * dd, o3 * dd);
        uint2 st;
        st.x = *reinterpret_cast<unsigned int*>(&pa);
        st.y = *reinterpret_cast<unsigned int*>(&pb);
        *reinterpret_cast<uint2*>(hp2 + (size_t)onode * 32 + cgrp * 4) = st;
    }
}

// agg layer2 + bias + relu + head (64 outcols). Same 8-entry gather structure.
__global__ __launch_bounds__(256)
void k_aggout(const __half* __restrict__ hp, const int* __restrict__ rowbeg,
              const int* __restrict__ rowend, const unsigned short* __restrict__ csr,
              const float* __restrict__ dinv, const float* __restrict__ b2,
              const float* __restrict__ Wo, const float* __restrict__ bo,
              float* __restrict__ out, int N) {
    __shared__ float aggT[32][33];
    __shared__ float Wosh[32 * 64];   // 8 KB
    int tid = threadIdx.x;
    int lane = tid & 63;
    int w = tid >> 6;
    int g = lane >> 2, q = lane & 3;
    int h = w & 1;
    int node_loc = (w >> 1) * 16 + g;
    int node = (int)blockIdx.x * 32 + node_loc;

    for (int i = tid; i < 1056; i += 256) (&aggT[0][0])[i] = 0.f;
    for (int i = tid; i < 512; i += 256)
        reinterpret_cast<float4*>(Wosh)[i] = reinterpret_cast<const float4*>(Wo)[i];
    __syncthreads();

    float acc[8], accB[8];
    #pragma unroll
    for (int t = 0; t < 8; ++t) { acc[t] = 0.f; accB[t] = 0.f; }
    int beg = 0, endx = 0;
    if (node < N) { beg = rowbeg[node]; endx = rowend[node]; }
    const uint4* hp4 = reinterpret_cast<const uint4*>(hp);
    for (int t = beg + 8 * h; t < endx; t += 16) {
        uint4 c4 = *reinterpret_cast<const uint4*>(csr + t);
        unsigned a0 = c4.x & 0xFFFFu, a1 = c4.x >> 16;
        unsigned a2 = c4.y & 0xFFFFu, a3 = c4.y >> 16;
        unsigned a4 = c4.z & 0xFFFFu, a5 = c4.z >> 16;
        unsigned a6 = c4.w & 0xFFFFu, a7 = c4.w >> 16;
        uint4 v0 = hp4[(size_t)a0 * 4 + q];
        uint4 v1 = hp4[(size_t)a1 * 4 + q];
        uint4 v2 = hp4[(size_t)a2 * 4 + q];
        uint4 v3 = hp4[(size_t)a3 * 4 + q];
        uint4 v4 = hp4[(size_t)a4 * 4 + q];
        uint4 v5 = hp4[(size_t)a5 * 4 + q];
        uint4 v6 = hp4[(size_t)a6 * 4 + q];
        uint4 v7 = hp4[(size_t)a7 * 4 + q];
        ACC8M(acc, v0); ACC8M(accB, v1); ACC8M(acc, v2); ACC8M(accB, v3);
        ACC8M(acc, v4); ACC8M(accB, v5); ACC8M(acc, v6); ACC8M(accB, v7);
    }
    #pragma unroll
    for (int j2 = 0; j2 < 8; ++j2)
        atomicAdd(&aggT[q * 8 + j2][node_loc], acc[j2] + accB[j2]);
    __syncthreads();

    // epilogue: 8 threads/node, 8 outcols each
    int nl2 = tid >> 3;
    int cgrp = tid & 7;               // cols cgrp*8..+7
    int onode = (int)blockIdx.x * 32 + nl2;
    float dd = (onode < N) ? dinv[onode] : 0.f;
    float o[8];
    #pragma unroll
    for (int i = 0; i < 8; ++i) o[i] = 0.f;
    #pragma unroll
    for (int k = 0; k < 32; ++k) {
        float yk = fmaxf(aggT[k][nl2] * dd + b2[k], 0.f);
        float4 wa = *reinterpret_cast<const float4*>(&Wosh[k * 64 + cgrp * 8]);
        float4 wb = *reinterpret_cast<const float4*>(&Wosh[k * 64 + cgrp * 8 + 4]);
        o[0] += yk * wa.x; o[1] += yk * wa.y; o[2] += yk * wa.z; o[3] += yk * wa.w;
        o[4] += yk * wb.x; o[5] += yk * wb.y; o[6] += yk * wb.z; o[7] += yk * wb.w;
    }
    if (onode < N) {
        float4 ba = *reinterpret_cast<const float4*>(bo + cgrp * 8);
        float4 bb = *reinterpret_cast<const float4*>(bo + cgrp * 8 + 4);
        float4 s0 = make_float4(o[0] + ba.x, o[1] + ba.y, o[2] + ba.z, o[3] + ba.w);
        float4 s1 = make_float4(o[4] + bb.x, o[5] + bb.y, o[6] + bb.z, o[7] + bb.w);
        float4* op = reinterpret_cast<float4*>(out + (size_t)onode * 64 + cgrp * 8);
        op[0] = s0;
        op[1] = s1;
    }
}

extern "C" void kernel_launch(void* const* d_in, const int* in_sizes, int n_in,
                              void* d_out, int out_size, void* d_ws, size_t ws_size,
                              hipStream_t stream) {
    const float* x  = (const float*)d_in[0];
    const int*   ei = (const int*)d_in[1];
    const float* W1 = (const float*)d_in[2];
    const float* b1 = (const float*)d_in[3];
    const float* W2 = (const float*)d_in[4];
    const float* b2 = (const float*)d_in[5];
    const float* Wo = (const float*)d_in[6];
    const float* bo = (const float*)d_in[7];
    float* out = (float*)d_out;

    const int N = in_sizes[0] / 128;   // 50000
    const int E = in_sizes[1] / 2;     // 1600000
    const int* src = ei;
    const int* dst = ei + E;

    char* ws = (char*)d_ws;
    size_t off = 0;
    auto alloc = [&](size_t bytes) {
        void* p = ws + off;
        off += (bytes + 255) & ~(size_t)255;
        return p;
    };
    int*            cursor = (int*)           alloc(512 * 4);
    unsigned int*   binned = (unsigned int*)  alloc((size_t)NBUCK * BCAP * 4);
    int*            rowbeg = (int*)           alloc((size_t)N * 4);
    int*            rowend = (int*)           alloc((size_t)N * 4);
    float*          dinv   = (float*)         alloc((size_t)N * 4);
    unsigned short* csr    = (unsigned short*)alloc((size_t)NBUCK * CCAP * 2);
    __half*         bufAh  = (__half*)        alloc((size_t)(N + 1) * 32 * 2);
    __half*         bufBh  = (__half*)        alloc((size_t)(N + 1) * 32 * 2);

    const int nbinA  = (E + CHUNK - 1) / CHUNK;      // 391
    const int nFront = NGEMM + nbinA;                // 489
    const int gAgg1  = (N + 1 + 31) / 32;            // covers pad node N
    const int gAgg2  = (N + 31) / 32;

    hipMemsetAsync(cursor, 0, 512 * 4, stream);
    k_front<<<nFront, 512, 0, stream>>>(x, W1, bufAh, N, src, dst, E,
                                        cursor, binned);
    k_binB<<<NBUCK, 512, 0, stream>>>(binned, cursor, rowbeg, rowend, dinv,
                                      csr, bufAh, N);
    k_aggmm1<<<gAgg1, 256, 0, stream>>>(bufAh, rowbeg, rowend, csr, dinv, b1,
                                        W2, bufBh, N);
    k_aggout<<<gAgg2, 256, 0, stream>>>(bufBh, rowbeg, rowend, csr, dinv, b2,
                                        Wo, bo, out, N);
}